// Round 6
// baseline (3724.284 us; speedup 1.0000x reference)
//
#include <hip/hip_runtime.h>
#include <cmath>
#include <cstdint>
#include <cfloat>

// ---------------------------------------------------------------------------
// CenterNet head, MI355X. Round 6: per-callsite kernel names (TAG), CC=8 conv
// tiles (bit-identical chain), LDS-staged f64 1x1, wh back to f32.
// Numerics contract (proven R3-R5, absmax 0.0):
//   - cls 3x3 convs: f32 fmaf chains, EXACT ci order (ci0 asc, cc, kh, kw).
//   - cls 1x1: f64 accum (ci 0..127 per o) -> correctly-rounded f32 logits.
//   - Selection on f32 logits, ties by lowest index.
// ---------------------------------------------------------------------------

#define CN_B   16
#define CN_H   128
#define CN_W   128
#define CN_HW  16384
#define CN_CLS 80
#define CN_K   100
#define NEG_SENT (-3.402823466e+38f)

__device__ __forceinline__ unsigned ordf(float v) {
    unsigned b = __float_as_uint(v);
    return (b >> 31) ? ~b : (b | 0x80000000u);
}
__device__ __forceinline__ float unordf(unsigned o) {
    return __uint_as_float((o >> 31) ? (o & 0x7fffffffu) : ~o);
}

// ---------------------------------------------------------------------------
// f32 3x3 conv, pad 1, bias + ReLU. Tile: 8 rows x 128 cols x 16 oc.
// CC=8 input-channel chunk (fewer barriers, 47KB LDS -> 3 blocks/CU).
// FMA chain: ci0 step 8, cc 0..7 => ci 0..CI-1 ascending — IDENTICAL to R3-R5.
// TAG only differentiates kernel names per call site for profiling.
// grid.x = Bc * 16 * (CO/16).
// ---------------------------------------------------------------------------
template<int CI, int TAG>
__global__ __launch_bounds__(256) void conv3x3_k(
    const float* __restrict__ in, const float* __restrict__ wgt,
    const float* __restrict__ bias, float* __restrict__ out, int CO)
{
    constexpr int CC = 8;
    const int bid = blockIdx.x;
    const int cob = CO >> 4;
    const int co0 = (bid % cob) * 16;
    const int tmp = bid / cob;
    const int h0  = (tmp & 15) * 8;
    const int b   = tmp >> 4;

    __shared__ float lin[CC][10][132];   // 42.2 KB
    __shared__ float lw[CC][9][16];      //  4.6 KB

    const int t   = threadIdx.x;
    const int col = t & 127;
    const int r2  = t >> 7;              // 0..1
    const int g   = t >> 6;              // 0..3; stages cc = g and g+4
    const int ln  = t & 63;

    float acc[4][16];
#pragma unroll
    for (int px = 0; px < 4; ++px)
#pragma unroll
        for (int o = 0; o < 16; ++o) acc[px][o] = 0.f;

    for (int ci0 = 0; ci0 < CI; ci0 += CC) {
        // ---- input staging: group g stages chunks g and g+4 ----
#pragma unroll
        for (int half = 0; half < 2; ++half) {
            const int cc = g + 4 * half;
            const float* base = in + (((size_t)b * CI + ci0 + cc) * CN_H) * CN_W;
#pragma unroll
            for (int rr = 0; rr < 10; ++rr) {
                const int srow = h0 - 1 + rr;
                const bool rok = (unsigned)srow < (unsigned)CN_H;
                const float* src = base + srow * CN_W;
#pragma unroll
                for (int q = 0; q < 2; ++q) {
                    const int lidx = ln + 64 * q;       // 0..127
                    const int scol = lidx - 1;
                    lin[cc][rr][lidx] =
                        (rok && (unsigned)scol < (unsigned)CN_W) ? src[scol] : 0.f;
                }
                if (ln < 2) {
                    const int lidx = 128 + ln;          // 128,129
                    const int scol = lidx - 1;          // 127,128
                    lin[cc][rr][lidx] =
                        (rok && (unsigned)scol < (unsigned)CN_W) ? src[scol] : 0.f;
                }
            }
        }
        // ---- weight staging ----
        for (int e = t; e < CC * 9 * 16; e += 256) {
            int cc  = e / 144;
            int rem = e % 144;
            int tap = rem / 16;
            int o   = rem % 16;
            lw[cc][tap][o] = wgt[(((size_t)(co0 + o)) * CI + ci0 + cc) * 9 + tap];
        }
        __syncthreads();
        // ---- compute: EXACT chain order (cc, kh, kw, px, o) ----
        for (int cc = 0; cc < CC; ++cc) {
#pragma unroll
            for (int kh = 0; kh < 3; ++kh) {
#pragma unroll
                for (int kw = 0; kw < 3; ++kw) {
#pragma unroll
                    for (int px = 0; px < 4; ++px) {
                        float v = lin[cc][r2 + 2 * px + kh][col + kw];
#pragma unroll
                        for (int o = 0; o < 16; ++o)
                            acc[px][o] = fmaf(v, lw[cc][kh * 3 + kw][o], acc[px][o]);
                    }
                }
            }
        }
        __syncthreads();
    }
#pragma unroll
    for (int px = 0; px < 4; ++px) {
        const int h = h0 + r2 + 2 * px;
#pragma unroll
        for (int o = 0; o < 16; ++o) {
            float v = acc[px][o] + bias[co0 + o];
            v = v > 0.f ? v : 0.f;
            out[(((size_t)b * CO + co0 + o) * CN_H + h) * CN_W + col] = v;
        }
    }
}

// ---------------------------------------------------------------------------
// 1x1 cls: 128 -> 80, f64 accumulate, LDS-staged px-tile (read h2 ONCE).
// Block: 256 px; stages h2[128ci][256px] f32 (128 KB), loops 5 oc-groups.
// Per-o chain: ci 0..127 ascending — identical f64 sum as R3-R5.
// grid = Bc * 64.
// ---------------------------------------------------------------------------
__global__ __launch_bounds__(256) void conv1x1_cls_k(
    const float* __restrict__ h2, const float* __restrict__ wgt,
    const float* __restrict__ bias, float* __restrict__ logits)
{
    constexpr int CI = 128;
    __shared__ float sh[CI][256];        // 128 KB

    const int t  = threadIdx.x;
    const int b  = blockIdx.x / 64;
    const int p0 = (blockIdx.x % 64) * 256;

    const float* src = h2 + (size_t)b * CI * CN_HW + p0;
    for (int ci = 0; ci < CI; ++ci)
        sh[ci][t] = src[(size_t)ci * CN_HW + t];
    __syncthreads();

    for (int og = 0; og < 5; ++og) {
        const int o0 = og * 16;
        double acc[16];
#pragma unroll
        for (int o = 0; o < 16; ++o) acc[o] = 0.0;

        for (int ci = 0; ci < CI; ++ci) {
            const double v = (double)sh[ci][t];
#pragma unroll
            for (int o = 0; o < 16; ++o)
                acc[o] += v * (double)wgt[(size_t)(o0 + o) * CI + ci];
        }
#pragma unroll
        for (int o = 0; o < 16; ++o)
            logits[((size_t)b * CN_CLS + o0 + o) * CN_HW + p0 + t] =
                (float)(acc[o] + (double)bias[o0 + o]);
    }
}

// ---------------------------------------------------------------------------
// 1x1 wh: 64 -> 4, f32, bias, ReLU, *16. grid Bc*64.
// ---------------------------------------------------------------------------
__global__ __launch_bounds__(256) void conv1x1_wh_k(
    const float* __restrict__ g2, const float* __restrict__ wgt,
    const float* __restrict__ bias, float* __restrict__ wh)
{
    constexpr int CI = 64;
    const int p = (blockIdx.x % 64) * 256 + threadIdx.x;
    const int b = blockIdx.x / 64;

    __shared__ float lw[CI][4];
    for (int e = threadIdx.x; e < CI * 4; e += 256) {
        int ci = e / 4, o = e % 4;
        lw[ci][o] = wgt[(size_t)o * CI + ci];
    }
    __syncthreads();

    float acc[4] = {0.f, 0.f, 0.f, 0.f};
    for (int ci = 0; ci < CI; ++ci) {
        float v = g2[((size_t)b * CI + ci) * CN_HW + p];
#pragma unroll
        for (int o = 0; o < 4; ++o) acc[o] = fmaf(v, lw[ci][o], acc[o]);
    }
#pragma unroll
    for (int o = 0; o < 4; ++o) {
        float v = acc[o] + bias[o];
        v = v > 0.f ? v : 0.f;
        wh[((size_t)b * 4 + o) * CN_HW + p] = v * 16.0f;
    }
}

// ---------------------------------------------------------------------------
// NMS + per-class top-100: LDS-staged logits, compaction + bitonic sort of
// (ordered_logit<<32 | ~index) keys; proven iterative-argmax fallback.
// ---------------------------------------------------------------------------
#define NMS_CAP 2048

__global__ __launch_bounds__(256) void nms_topk_k(
    const float* __restrict__ logits,
    float* __restrict__ pc_logit,    // [B,8000] @ bg*8000 + c*100 + k
    int*   __restrict__ pc_ind,
    int b0)
{
    __shared__ float sc[CN_HW];                   // 64 KB
    __shared__ unsigned long long cand[NMS_CAP];  // 16 KB
    __shared__ int   cnt;
    __shared__ float rv[4];
    __shared__ int   ri[4];
    __shared__ int   pick;

    const int bc = blockIdx.x;
    const int bl = bc / CN_CLS;
    const int c  = bc % CN_CLS;
    const int bg = b0 + bl;
    const int t  = threadIdx.x;
    const float* L = logits + (size_t)bc * CN_HW;

    if (t == 0) cnt = 0;
    {
        const float4* L4 = (const float4*)L;
        float4* s4 = (float4*)sc;
        for (int p = t; p < CN_HW / 4; p += 256) s4[p] = L4[p];
    }
    __syncthreads();

    unsigned long long flags = 0;
    for (int k = 0; k < 64; ++k) {
        const int p   = t + 256 * k;
        const int row = p >> 7, cl = p & 127;
        const float c0 = sc[p];
        bool mx = true;
#pragma unroll
        for (int dr = -1; dr <= 1; ++dr)
#pragma unroll
            for (int dc = -1; dc <= 1; ++dc) {
                if (dr == 0 && dc == 0) continue;
                int rr = row + dr, cc2 = cl + dc;
                if ((unsigned)rr < (unsigned)CN_H && (unsigned)cc2 < (unsigned)CN_W)
                    if (sc[(rr << 7) + cc2] > c0) mx = false;
            }
        if (mx) flags |= 1ull << k;
    }
    __syncthreads();

    {
        unsigned long long f = flags;
        while (f) {
            int k = __ffsll((long long)f) - 1;
            f &= f - 1;
            const int p = t + 256 * k;
            const int slot = atomicAdd(&cnt, 1);
            if (slot < NMS_CAP)
                cand[slot] = ((unsigned long long)ordf(sc[p]) << 32) | (unsigned)(~p);
        }
    }
    __syncthreads();
    const int M = cnt;

    if (M >= CN_K && M <= NMS_CAP) {
        int P = 128;
        while (P < M) P <<= 1;
        for (int i = M + t; i < P; i += 256) cand[i] = 0ull;
        __syncthreads();
        for (int k = 2; k <= P; k <<= 1) {
            for (int j = k >> 1; j > 0; j >>= 1) {
                for (int n = t; n < (P >> 1); n += 256) {
                    const int i = ((n & ~(j - 1)) << 1) | (n & (j - 1));
                    const int m = i | j;
                    const unsigned long long a = cand[i], bqq = cand[m];
                    const bool up = ((i & k) == 0);
                    if (up ? (a < bqq) : (a > bqq)) { cand[i] = bqq; cand[m] = a; }
                }
                __syncthreads();
            }
        }
        if (t < CN_K) {
            const unsigned long long key = cand[t];
            const int p = (int)(~(unsigned)key) & 0xFFFF;
            pc_logit[(size_t)bg * 8000 + c * CN_K + t] = unordf((unsigned)(key >> 32));
            pc_ind  [(size_t)bg * 8000 + c * CN_K + t] = p;
        }
    } else {
        unsigned long long removed = 0;
        for (int it = 0; it < CN_K; ++it) {
            float bv = -INFINITY;
            int   bi = 0x7fffffff;
            for (int k = 0; k < 64; ++k) {
                if ((removed >> k) & 1) continue;
                const int p = t + 256 * k;
                const float v = ((flags >> k) & 1) ? sc[p] : NEG_SENT;
                if (v > bv || (v == bv && p < bi)) { bv = v; bi = p; }
            }
#pragma unroll
            for (int off = 32; off; off >>= 1) {
                float ov = __shfl_down(bv, off);
                int   oi = __shfl_down(bi, off);
                if (ov > bv || (ov == bv && oi < bi)) { bv = ov; bi = oi; }
            }
            const int wid = t >> 6;
            if ((t & 63) == 0) { rv[wid] = bv; ri[wid] = bi; }
            __syncthreads();
            if (t == 0) {
                for (int wv = 1; wv < 4; ++wv)
                    if (rv[wv] > bv || (rv[wv] == bv && ri[wv] < bi)) { bv = rv[wv]; bi = ri[wv]; }
                pc_logit[(size_t)bg * 8000 + c * CN_K + it] = bv;
                pc_ind  [(size_t)bg * 8000 + c * CN_K + it] = bi;
                pick = bi;
            }
            __syncthreads();
            const int pk = pick;
            if ((pk & 255) == t) removed |= 1ull << (pk >> 8);
            __syncthreads();
        }
    }
}

// ---------------------------------------------------------------------------
// Global top-100 of 8000 via bitonic sort of 8192 keys + sigmoid + gather.
// ---------------------------------------------------------------------------
__global__ __launch_bounds__(256) void global_out_k(
    const float* __restrict__ pc_logit, const int* __restrict__ pc_ind,
    const float* __restrict__ wh, float* __restrict__ out)
{
    constexpr int N = CN_CLS * CN_K;   // 8000
    constexpr int P = 8192;
    __shared__ unsigned long long gk[P];

    const int b = blockIdx.x;
    const int t = threadIdx.x;

    for (int n = t; n < P; n += 256) {
        unsigned long long key = 0ull;
        if (n < N) {
            const float v = pc_logit[(size_t)b * N + n];
            key = ((unsigned long long)ordf(v) << 32) | (unsigned)(~n);
        }
        gk[n] = key;
    }
    __syncthreads();

    for (int k = 2; k <= P; k <<= 1) {
        for (int j = k >> 1; j > 0; j >>= 1) {
            for (int n = t; n < (P >> 1); n += 256) {
                const int i = ((n & ~(j - 1)) << 1) | (n & (j - 1));
                const int m = i | j;
                const unsigned long long a = gk[i], bqq = gk[m];
                const bool up = ((i & k) == 0);
                if (up ? (a < bqq) : (a > bqq)) { gk[i] = bqq; gk[m] = a; }
            }
            __syncthreads();
        }
    }

    if (t < CN_K) {
        const unsigned long long key = gk[t];
        const int   flat  = (int)(~(unsigned)key) & 0x3FFF;
        const float logit = unordf((unsigned)(key >> 32));
        const int   cls   = flat / CN_K;
        const int   ind   = pc_ind[(size_t)b * N + flat];
        const float score = (float)(1.0 / (1.0 + exp(-(double)logit)));
        const float ys = (float)(ind >> 7) * 4.0f;
        const float xs = (float)(ind & 127) * 4.0f;
        const float wl = wh[((size_t)b * 4 + 0) * CN_HW + ind];
        const float wt = wh[((size_t)b * 4 + 1) * CN_HW + ind];
        const float wr = wh[((size_t)b * 4 + 2) * CN_HW + ind];
        const float wb = wh[((size_t)b * 4 + 3) * CN_HW + ind];
        float* row = out + ((size_t)b * CN_K + t) * 6;
        row[0] = xs - wl;
        row[1] = ys - wt;
        row[2] = xs + wr;
        row[3] = ys + wb;
        row[4] = score;
        row[5] = (float)cls;
        out[CN_B * CN_K * 6 + b * CN_K + t] = (score > 0.01f) ? 1.0f : 0.0f;
    }
}

// ---------------------------------------------------------------------------
extern "C" void kernel_launch(void* const* d_in, const int* in_sizes, int n_in,
                              void* d_out, int out_size, void* d_ws, size_t ws_size,
                              hipStream_t stream)
{
    (void)in_sizes; (void)n_in; (void)out_size;

    const float* x      = (const float*)d_in[0];
    const float* cls_w1 = (const float*)d_in[1];
    const float* cls_b1 = (const float*)d_in[2];
    const float* cls_w2 = (const float*)d_in[3];
    const float* cls_b2 = (const float*)d_in[4];
    const float* cls_w3 = (const float*)d_in[5];
    const float* cls_b3 = (const float*)d_in[6];
    const float* wh_w1  = (const float*)d_in[7];
    const float* wh_b1  = (const float*)d_in[8];
    const float* wh_w2  = (const float*)d_in[9];
    const float* wh_b2  = (const float*)d_in[10];
    const float* wh_w3  = (const float*)d_in[11];
    const float* wh_b3  = (const float*)d_in[12];
    float* out = (float*)d_out;

    const size_t PERA = 8388608u, PERB = 8388608u;
    const size_t PERS = 4194304u + 512000u + 512000u;
    int Bc = 1;
    {
        const int cand_[5] = {16, 8, 4, 2, 1};
        for (int i = 0; i < 5; ++i) {
            if ((size_t)cand_[i] * (PERA + PERB) + PERS <= ws_size) { Bc = cand_[i]; break; }
        }
    }

    char* ws = (char*)d_ws;
    char*  regA  = ws;
    char*  regB  = ws + (size_t)Bc * PERA;
    float* whbuf = (float*)(ws + (size_t)Bc * (PERA + PERB));
    float* pc_s  = (float*)((char*)whbuf + 4194304u);
    int*   pc_i  = (int*)((char*)pc_s + 512000u);

    dim3 blk(256);

    for (int b0 = 0; b0 < CN_B; b0 += Bc) {
        const float* xc = x + (size_t)b0 * 64 * CN_HW;
        float* g1     = (float*)regA;
        float* g2     = (float*)regB;
        float* h1     = (float*)regA;
        float* h2     = (float*)regB;
        float* logits = (float*)regA;
        float* whc    = whbuf + (size_t)b0 * 4 * CN_HW;

        // wh branch (f32, proven)
        conv3x3_k<64, 3><<<dim3(Bc * 16 * 4), blk, 0, stream>>>(xc, wh_w1, wh_b1, g1, 64);
        conv3x3_k<64, 4><<<dim3(Bc * 16 * 4), blk, 0, stream>>>(g1, wh_w2, wh_b2, g2, 64);
        conv1x1_wh_k<<<dim3(Bc * 64), blk, 0, stream>>>(g2, wh_w3, wh_b3, whc);

        // cls branch: f32 3x3 convs (bit-identical chains), f64-accum 1x1
        conv3x3_k<64, 1><<<dim3(Bc * 16 * 8), blk, 0, stream>>>(xc, cls_w1, cls_b1, h1, 128);
        conv3x3_k<128, 2><<<dim3(Bc * 16 * 8), blk, 0, stream>>>(h1, cls_w2, cls_b2, h2, 128);
        conv1x1_cls_k<<<dim3(Bc * 64), blk, 0, stream>>>(h2, cls_w3, cls_b3, logits);

        // per-class selection (LDS-staged bitonic)
        nms_topk_k<<<dim3(Bc * CN_CLS), blk, 0, stream>>>(logits, pc_s, pc_i, b0);
    }

    global_out_k<<<dim3(CN_B), blk, 0, stream>>>(pc_s, pc_i, whbuf, out);
}

// Round 7
// 3116.453 us; speedup vs baseline: 1.1950x; 1.1950x over previous
//
#include <hip/hip_runtime.h>
#include <cmath>
#include <cstdint>
#include <cfloat>

// ---------------------------------------------------------------------------
// CenterNet head, MI355X. Round 7: XCD-chunked block swizzle (T1) on the
// reuse-heavy kernels; conv3x3/conv1x1 bodies reverted to proven R5 forms.
// Numerics contract (proven R3-R5, absmax 0.0):
//   - cls 3x3 convs: f32 fmaf chains, EXACT ci order (ci0 asc, cc, kh, kw).
//   - cls 1x1: f64 accum (ci 0..127 per o) -> correctly-rounded f32 logits.
//   - Selection on f32 logits, ties by lowest index.
// Swizzle is a pure permutation of blockIdx -> work; outputs bit-identical.
// ---------------------------------------------------------------------------

#define CN_B   16
#define CN_H   128
#define CN_W   128
#define CN_HW  16384
#define CN_CLS 80
#define CN_K   100
#define NEG_SENT (-3.402823466e+38f)

__device__ __forceinline__ unsigned ordf(float v) {
    unsigned b = __float_as_uint(v);
    return (b >> 31) ? ~b : (b | 0x80000000u);
}
__device__ __forceinline__ float unordf(unsigned o) {
    return __uint_as_float((o >> 31) ? (o & 0x7fffffffu) : ~o);
}

// Bijective chunked XCD transform (m204): hardware assigns dispatch-index d
// to XCD d%8; this maps each XCD to a CONTIGUOUS chunk of work-ids so blocks
// sharing input stripes run on the same per-XCD L2.
__device__ __forceinline__ int xcd_swz(int bid, int nwg) {
    const int q = nwg >> 3, r = nwg & 7;
    const int x = bid & 7, off = bid >> 3;
    return (x < r ? x * (q + 1) : r * (q + 1) + (x - r) * q) + off;
}

// ---------------------------------------------------------------------------
// f32 3x3 conv, pad 1, bias + ReLU. Tile: 8 rows x 128 cols x 16 oc. CC=4.
// Work decode: oc-tile fastest -> one XCD chunk = whole stripes x all oc.
// FMA chain identical to R3-R5 (ci0 asc, cc, kh, kw, px, o).
// grid.x = Bc * 16 * (CO/16).
// ---------------------------------------------------------------------------
template<int CI, int TAG>
__global__ __launch_bounds__(256) void conv3x3_k(
    const float* __restrict__ in, const float* __restrict__ wgt,
    const float* __restrict__ bias, float* __restrict__ out, int CO)
{
    constexpr int CC = 4;
    const int wg  = xcd_swz(blockIdx.x, gridDim.x);
    const int cob = CO >> 4;
    const int co0 = (wg % cob) * 16;
    const int tmp = wg / cob;
    const int h0  = (tmp & 15) * 8;
    const int b   = tmp >> 4;

    __shared__ float lin[CC][10][132];   // rows h0-1..h0+8, cols -1..128 @+1
    __shared__ float lw[CC][9][16];

    const int t   = threadIdx.x;
    const int col = t & 127;
    const int r2  = t >> 7;              // 0..1
    const int g   = t >> 6;              // staging cc 0..3
    const int ln  = t & 63;

    float acc[4][16];
#pragma unroll
    for (int px = 0; px < 4; ++px)
#pragma unroll
        for (int o = 0; o < 16; ++o) acc[px][o] = 0.f;

    for (int ci0 = 0; ci0 < CI; ci0 += CC) {
        // ---- input staging: no div/mod, coalesced ----
        {
            const float* base = in + (((size_t)b * CI + ci0 + g) * CN_H) * CN_W;
#pragma unroll
            for (int rr = 0; rr < 10; ++rr) {
                const int srow = h0 - 1 + rr;
                const bool rok = (unsigned)srow < (unsigned)CN_H;
                const float* src = base + srow * CN_W;
#pragma unroll
                for (int q = 0; q < 2; ++q) {
                    const int lidx = ln + 64 * q;       // 0..127
                    const int scol = lidx - 1;
                    lin[g][rr][lidx] =
                        (rok && (unsigned)scol < (unsigned)CN_W) ? src[scol] : 0.f;
                }
                if (ln < 2) {
                    const int lidx = 128 + ln;          // 128,129
                    const int scol = lidx - 1;          // 127,128
                    lin[g][rr][lidx] =
                        (rok && (unsigned)scol < (unsigned)CN_W) ? src[scol] : 0.f;
                }
            }
        }
        // ---- weight staging ----
        for (int e = t; e < CC * 9 * 16; e += 256) {
            int cc  = e / 144;
            int rem = e % 144;
            int tap = rem / 16;
            int o   = rem % 16;
            lw[cc][tap][o] = wgt[(((size_t)(co0 + o)) * CI + ci0 + cc) * 9 + tap];
        }
        __syncthreads();
        // ---- compute: EXACT R3-R5 chain order ----
        for (int cc = 0; cc < CC; ++cc) {
#pragma unroll
            for (int kh = 0; kh < 3; ++kh) {
#pragma unroll
                for (int kw = 0; kw < 3; ++kw) {
#pragma unroll
                    for (int px = 0; px < 4; ++px) {
                        float v = lin[cc][r2 + 2 * px + kh][col + kw];
#pragma unroll
                        for (int o = 0; o < 16; ++o)
                            acc[px][o] = fmaf(v, lw[cc][kh * 3 + kw][o], acc[px][o]);
                    }
                }
            }
        }
        __syncthreads();
    }
#pragma unroll
    for (int px = 0; px < 4; ++px) {
        const int h = h0 + r2 + 2 * px;
#pragma unroll
        for (int o = 0; o < 16; ++o) {
            float v = acc[px][o] + bias[co0 + o];
            v = v > 0.f ? v : 0.f;
            out[(((size_t)b * CO + co0 + o) * CN_H + h) * CN_W + col] = v;
        }
    }
}

// ---------------------------------------------------------------------------
// 1x1 cls: 128 -> 80, f64 accumulate, bias, round to f32. R5 body; 1D grid
// Bc*64*5 with og FASTEST after XCD transform -> a px-block's 5 oc-groups run
// consecutively on one XCD (h2 tile stays in its L2; h2 read from HBM once).
// Per-o chain: ci 0..127 ascending — identical f64 sum as R3-R6.
// ---------------------------------------------------------------------------
__global__ __launch_bounds__(256) void conv1x1_cls_k(
    const float* __restrict__ h2, const float* __restrict__ wgt,
    const float* __restrict__ bias, float* __restrict__ logits)
{
    constexpr int CI = 128;
    const int wg = xcd_swz(blockIdx.x, gridDim.x);
    const int og = wg % 5;
    const int pb = wg / 5;
    const int b  = pb / 64;
    const int p  = (pb % 64) * 256 + threadIdx.x;
    const int o0 = og * 16;

    __shared__ double lw[CI][16];
    for (int e = threadIdx.x; e < CI * 16; e += 256) {
        int ci = e / 16, o = e % 16;
        lw[ci][o] = (double)wgt[(size_t)(o0 + o) * CI + ci];
    }
    __syncthreads();

    double acc[16];
#pragma unroll
    for (int o = 0; o < 16; ++o) acc[o] = 0.0;

    for (int ci = 0; ci < CI; ++ci) {
        double v = (double)h2[((size_t)b * CI + ci) * CN_HW + p];
#pragma unroll
        for (int o = 0; o < 16; ++o) acc[o] += v * lw[ci][o];
    }
#pragma unroll
    for (int o = 0; o < 16; ++o)
        logits[((size_t)b * CN_CLS + o0 + o) * CN_HW + p] =
            (float)(acc[o] + (double)bias[o0 + o]);
}

// ---------------------------------------------------------------------------
// 1x1 wh: 64 -> 4, f32, bias, ReLU, *16. grid Bc*64. (single-pass, no swizzle)
// ---------------------------------------------------------------------------
__global__ __launch_bounds__(256) void conv1x1_wh_k(
    const float* __restrict__ g2, const float* __restrict__ wgt,
    const float* __restrict__ bias, float* __restrict__ wh)
{
    constexpr int CI = 64;
    const int p = (blockIdx.x % 64) * 256 + threadIdx.x;
    const int b = blockIdx.x / 64;

    __shared__ float lw[CI][4];
    for (int e = threadIdx.x; e < CI * 4; e += 256) {
        int ci = e / 4, o = e % 4;
        lw[ci][o] = wgt[(size_t)o * CI + ci];
    }
    __syncthreads();

    float acc[4] = {0.f, 0.f, 0.f, 0.f};
    for (int ci = 0; ci < CI; ++ci) {
        float v = g2[((size_t)b * CI + ci) * CN_HW + p];
#pragma unroll
        for (int o = 0; o < 4; ++o) acc[o] = fmaf(v, lw[ci][o], acc[o]);
    }
#pragma unroll
    for (int o = 0; o < 4; ++o) {
        float v = acc[o] + bias[o];
        v = v > 0.f ? v : 0.f;
        wh[((size_t)b * 4 + o) * CN_HW + p] = v * 16.0f;
    }
}

// ---------------------------------------------------------------------------
// NMS + per-class top-100: LDS-staged logits, compaction + bitonic sort of
// (ordered_logit<<32 | ~index) keys; proven iterative-argmax fallback.
// ---------------------------------------------------------------------------
#define NMS_CAP 2048

__global__ __launch_bounds__(256) void nms_topk_k(
    const float* __restrict__ logits,
    float* __restrict__ pc_logit,    // [B,8000] @ bg*8000 + c*100 + k
    int*   __restrict__ pc_ind,
    int b0)
{
    __shared__ float sc[CN_HW];                   // 64 KB
    __shared__ unsigned long long cand[NMS_CAP];  // 16 KB
    __shared__ int   cnt;
    __shared__ float rv[4];
    __shared__ int   ri[4];
    __shared__ int   pick;

    const int bc = blockIdx.x;
    const int bl = bc / CN_CLS;
    const int c  = bc % CN_CLS;
    const int bg = b0 + bl;
    const int t  = threadIdx.x;
    const float* L = logits + (size_t)bc * CN_HW;

    if (t == 0) cnt = 0;
    {
        const float4* L4 = (const float4*)L;
        float4* s4 = (float4*)sc;
        for (int p = t; p < CN_HW / 4; p += 256) s4[p] = L4[p];
    }
    __syncthreads();

    unsigned long long flags = 0;
    for (int k = 0; k < 64; ++k) {
        const int p   = t + 256 * k;
        const int row = p >> 7, cl = p & 127;
        const float c0 = sc[p];
        bool mx = true;
#pragma unroll
        for (int dr = -1; dr <= 1; ++dr)
#pragma unroll
            for (int dc = -1; dc <= 1; ++dc) {
                if (dr == 0 && dc == 0) continue;
                int rr = row + dr, cc2 = cl + dc;
                if ((unsigned)rr < (unsigned)CN_H && (unsigned)cc2 < (unsigned)CN_W)
                    if (sc[(rr << 7) + cc2] > c0) mx = false;
            }
        if (mx) flags |= 1ull << k;
    }
    __syncthreads();

    {
        unsigned long long f = flags;
        while (f) {
            int k = __ffsll((long long)f) - 1;
            f &= f - 1;
            const int p = t + 256 * k;
            const int slot = atomicAdd(&cnt, 1);
            if (slot < NMS_CAP)
                cand[slot] = ((unsigned long long)ordf(sc[p]) << 32) | (unsigned)(~p);
        }
    }
    __syncthreads();
    const int M = cnt;

    if (M >= CN_K && M <= NMS_CAP) {
        int P = 128;
        while (P < M) P <<= 1;
        for (int i = M + t; i < P; i += 256) cand[i] = 0ull;
        __syncthreads();
        for (int k = 2; k <= P; k <<= 1) {
            for (int j = k >> 1; j > 0; j >>= 1) {
                for (int n = t; n < (P >> 1); n += 256) {
                    const int i = ((n & ~(j - 1)) << 1) | (n & (j - 1));
                    const int m = i | j;
                    const unsigned long long a = cand[i], bqq = cand[m];
                    const bool up = ((i & k) == 0);
                    if (up ? (a < bqq) : (a > bqq)) { cand[i] = bqq; cand[m] = a; }
                }
                __syncthreads();
            }
        }
        if (t < CN_K) {
            const unsigned long long key = cand[t];
            const int p = (int)(~(unsigned)key) & 0xFFFF;
            pc_logit[(size_t)bg * 8000 + c * CN_K + t] = unordf((unsigned)(key >> 32));
            pc_ind  [(size_t)bg * 8000 + c * CN_K + t] = p;
        }
    } else {
        unsigned long long removed = 0;
        for (int it = 0; it < CN_K; ++it) {
            float bv = -INFINITY;
            int   bi = 0x7fffffff;
            for (int k = 0; k < 64; ++k) {
                if ((removed >> k) & 1) continue;
                const int p = t + 256 * k;
                const float v = ((flags >> k) & 1) ? sc[p] : NEG_SENT;
                if (v > bv || (v == bv && p < bi)) { bv = v; bi = p; }
            }
#pragma unroll
            for (int off = 32; off; off >>= 1) {
                float ov = __shfl_down(bv, off);
                int   oi = __shfl_down(bi, off);
                if (ov > bv || (ov == bv && oi < bi)) { bv = ov; bi = oi; }
            }
            const int wid = t >> 6;
            if ((t & 63) == 0) { rv[wid] = bv; ri[wid] = bi; }
            __syncthreads();
            if (t == 0) {
                for (int wv = 1; wv < 4; ++wv)
                    if (rv[wv] > bv || (rv[wv] == bv && ri[wv] < bi)) { bv = rv[wv]; bi = ri[wv]; }
                pc_logit[(size_t)bg * 8000 + c * CN_K + it] = bv;
                pc_ind  [(size_t)bg * 8000 + c * CN_K + it] = bi;
                pick = bi;
            }
            __syncthreads();
            const int pk = pick;
            if ((pk & 255) == t) removed |= 1ull << (pk >> 8);
            __syncthreads();
        }
    }
}

// ---------------------------------------------------------------------------
// Global top-100 of 8000 via bitonic sort of 8192 keys + sigmoid + gather.
// ---------------------------------------------------------------------------
__global__ __launch_bounds__(256) void global_out_k(
    const float* __restrict__ pc_logit, const int* __restrict__ pc_ind,
    const float* __restrict__ wh, float* __restrict__ out)
{
    constexpr int N = CN_CLS * CN_K;   // 8000
    constexpr int P = 8192;
    __shared__ unsigned long long gk[P];

    const int b = blockIdx.x;
    const int t = threadIdx.x;

    for (int n = t; n < P; n += 256) {
        unsigned long long key = 0ull;
        if (n < N) {
            const float v = pc_logit[(size_t)b * N + n];
            key = ((unsigned long long)ordf(v) << 32) | (unsigned)(~n);
        }
        gk[n] = key;
    }
    __syncthreads();

    for (int k = 2; k <= P; k <<= 1) {
        for (int j = k >> 1; j > 0; j >>= 1) {
            for (int n = t; n < (P >> 1); n += 256) {
                const int i = ((n & ~(j - 1)) << 1) | (n & (j - 1));
                const int m = i | j;
                const unsigned long long a = gk[i], bqq = gk[m];
                const bool up = ((i & k) == 0);
                if (up ? (a < bqq) : (a > bqq)) { gk[i] = bqq; gk[m] = a; }
            }
            __syncthreads();
        }
    }

    if (t < CN_K) {
        const unsigned long long key = gk[t];
        const int   flat  = (int)(~(unsigned)key) & 0x3FFF;
        const float logit = unordf((unsigned)(key >> 32));
        const int   cls   = flat / CN_K;
        const int   ind   = pc_ind[(size_t)b * N + flat];
        const float score = (float)(1.0 / (1.0 + exp(-(double)logit)));
        const float ys = (float)(ind >> 7) * 4.0f;
        const float xs = (float)(ind & 127) * 4.0f;
        const float wl = wh[((size_t)b * 4 + 0) * CN_HW + ind];
        const float wt = wh[((size_t)b * 4 + 1) * CN_HW + ind];
        const float wr = wh[((size_t)b * 4 + 2) * CN_HW + ind];
        const float wb = wh[((size_t)b * 4 + 3) * CN_HW + ind];
        float* row = out + ((size_t)b * CN_K + t) * 6;
        row[0] = xs - wl;
        row[1] = ys - wt;
        row[2] = xs + wr;
        row[3] = ys + wb;
        row[4] = score;
        row[5] = (float)cls;
        out[CN_B * CN_K * 6 + b * CN_K + t] = (score > 0.01f) ? 1.0f : 0.0f;
    }
}

// ---------------------------------------------------------------------------
extern "C" void kernel_launch(void* const* d_in, const int* in_sizes, int n_in,
                              void* d_out, int out_size, void* d_ws, size_t ws_size,
                              hipStream_t stream)
{
    (void)in_sizes; (void)n_in; (void)out_size;

    const float* x      = (const float*)d_in[0];
    const float* cls_w1 = (const float*)d_in[1];
    const float* cls_b1 = (const float*)d_in[2];
    const float* cls_w2 = (const float*)d_in[3];
    const float* cls_b2 = (const float*)d_in[4];
    const float* cls_w3 = (const float*)d_in[5];
    const float* cls_b3 = (const float*)d_in[6];
    const float* wh_w1  = (const float*)d_in[7];
    const float* wh_b1  = (const float*)d_in[8];
    const float* wh_w2  = (const float*)d_in[9];
    const float* wh_b2  = (const float*)d_in[10];
    const float* wh_w3  = (const float*)d_in[11];
    const float* wh_b3  = (const float*)d_in[12];
    float* out = (float*)d_out;

    const size_t PERA = 8388608u, PERB = 8388608u;
    const size_t PERS = 4194304u + 512000u + 512000u;
    int Bc = 1;
    {
        const int cand_[5] = {16, 8, 4, 2, 1};
        for (int i = 0; i < 5; ++i) {
            if ((size_t)cand_[i] * (PERA + PERB) + PERS <= ws_size) { Bc = cand_[i]; break; }
        }
    }

    char* ws = (char*)d_ws;
    char*  regA  = ws;
    char*  regB  = ws + (size_t)Bc * PERA;
    float* whbuf = (float*)(ws + (size_t)Bc * (PERA + PERB));
    float* pc_s  = (float*)((char*)whbuf + 4194304u);
    int*   pc_i  = (int*)((char*)pc_s + 512000u);

    dim3 blk(256);

    for (int b0 = 0; b0 < CN_B; b0 += Bc) {
        const float* xc = x + (size_t)b0 * 64 * CN_HW;
        float* g1     = (float*)regA;
        float* g2     = (float*)regB;
        float* h1     = (float*)regA;
        float* h2     = (float*)regB;
        float* logits = (float*)regA;
        float* whc    = whbuf + (size_t)b0 * 4 * CN_HW;

        // wh branch (f32, proven)
        conv3x3_k<64, 3><<<dim3(Bc * 16 * 4), blk, 0, stream>>>(xc, wh_w1, wh_b1, g1, 64);
        conv3x3_k<64, 4><<<dim3(Bc * 16 * 4), blk, 0, stream>>>(g1, wh_w2, wh_b2, g2, 64);
        conv1x1_wh_k<<<dim3(Bc * 64), blk, 0, stream>>>(g2, wh_w3, wh_b3, whc);

        // cls branch: f32 3x3 convs (bit-identical chains), f64-accum 1x1
        conv3x3_k<64, 1><<<dim3(Bc * 16 * 8), blk, 0, stream>>>(xc, cls_w1, cls_b1, h1, 128);
        conv3x3_k<128, 2><<<dim3(Bc * 16 * 8), blk, 0, stream>>>(h1, cls_w2, cls_b2, h2, 128);
        conv1x1_cls_k<<<dim3(Bc * 64 * 5), blk, 0, stream>>>(h2, cls_w3, cls_b3, logits);

        // per-class selection (LDS-staged bitonic)
        nms_topk_k<<<dim3(Bc * CN_CLS), blk, 0, stream>>>(logits, pc_s, pc_i, b0);
    }

    global_out_k<<<dim3(CN_B), blk, 0, stream>>>(pc_s, pc_i, whbuf, out);
}

// Round 8
// 2998.987 us; speedup vs baseline: 1.2418x; 1.0392x over previous
//
#include <hip/hip_runtime.h>
#include <cmath>
#include <cstdint>
#include <cfloat>

// ---------------------------------------------------------------------------
// CenterNet head, MI355X. Round 8: SGPR-path conv weights (pre-transposed),
// sparse wh at selected pixels only, distinct kernel names per layer.
// Numerics contract (proven R3-R7, absmax 0.0):
//   - cls 3x3 convs: f32 fmaf chains, EXACT per-output order (ci asc, kh, kw).
//   - cls 1x1: f64 accum (ci 0..127) -> correctly-rounded f32 logits.
//   - Selection on f32 logits, ties by lowest index.
//   - wh: loose tolerance (10.08, bf16-rounded compare) -> sparse f32 recompute.
// ---------------------------------------------------------------------------

#define CN_B   16
#define CN_H   128
#define CN_W   128
#define CN_HW  16384
#define CN_CLS 80
#define CN_K   100
#define NEG_SENT (-3.402823466e+38f)

__device__ __forceinline__ unsigned ordf(float v) {
    unsigned b = __float_as_uint(v);
    return (b >> 31) ? ~b : (b | 0x80000000u);
}
__device__ __forceinline__ float unordf(unsigned o) {
    return __uint_as_float((o >> 31) ? (o & 0x7fffffffu) : ~o);
}

// Bijective chunked XCD transform (m204): XCD x gets a contiguous chunk.
__device__ __forceinline__ int xcd_swz(int bid, int nwg) {
    const int q = nwg >> 3, r = nwg & 7;
    const int x = bid & 7, off = bid >> 3;
    return (x < r ? x * (q + 1) : r * (q + 1) + (x - r) * q) + off;
}

// ---------------------------------------------------------------------------
// Weight transpose (bit-copy): wt[(ci*9+tap)*CO + co] = w[co][ci][tap].
// ---------------------------------------------------------------------------
__global__ __launch_bounds__(256) void wtr_k(
    const float* __restrict__ w, float* __restrict__ wt, int CI, int CO)
{
    const int e = blockIdx.x * 256 + threadIdx.x;
    const int n = CI * 9 * CO;
    if (e < n) {
        const int co = e % CO;
        const int rest = e / CO;            // ci*9 + tap
        wt[e] = w[(size_t)co * CI * 9 + rest];
    }
}

// ---------------------------------------------------------------------------
// f32 3x3 conv, pad 1, bias + ReLU. Tile: 8 rows x 128 cols x 16 oc. CC=4.
// Weights read as wave-uniform scalars from transposed layout (SGPR operands,
// no weight LDS). Per-(px,o) fmaf chain: (ci0 asc, cc, kh, kw) — IDENTICAL
// bits to R3-R7. grid.x = Bc * 16 * (CO/16), co-tile fastest + XCD swizzle.
// ---------------------------------------------------------------------------
template<int CI>
__device__ __forceinline__ void conv3x3_body(
    const float* __restrict__ in, const float* __restrict__ wt,
    const float* __restrict__ bias, float* __restrict__ out, int CO)
{
    constexpr int CC = 4;
    const int wg  = xcd_swz(blockIdx.x, gridDim.x);
    const int cob = CO >> 4;
    const int co0 = (wg % cob) * 16;
    const int tmp = wg / cob;
    const int h0  = (tmp & 15) * 8;
    const int b   = tmp >> 4;

    __shared__ float lin[CC][10][132];   // 21.1 KB

    const int t   = threadIdx.x;
    const int col = t & 127;
    const int r2  = t >> 7;              // 0..1
    const int g   = t >> 6;              // staging cc 0..3
    const int ln  = t & 63;

    float acc[4][16];
#pragma unroll
    for (int px = 0; px < 4; ++px)
#pragma unroll
        for (int o = 0; o < 16; ++o) acc[px][o] = 0.f;

    for (int ci0 = 0; ci0 < CI; ci0 += CC) {
        // ---- input staging (proven R5 form) ----
        {
            const float* base = in + (((size_t)b * CI + ci0 + g) * CN_H) * CN_W;
#pragma unroll
            for (int rr = 0; rr < 10; ++rr) {
                const int srow = h0 - 1 + rr;
                const bool rok = (unsigned)srow < (unsigned)CN_H;
                const float* src = base + srow * CN_W;
#pragma unroll
                for (int q = 0; q < 2; ++q) {
                    const int lidx = ln + 64 * q;
                    const int scol = lidx - 1;
                    lin[g][rr][lidx] =
                        (rok && (unsigned)scol < (unsigned)CN_W) ? src[scol] : 0.f;
                }
                if (ln < 2) {
                    const int lidx = 128 + ln;
                    const int scol = lidx - 1;
                    lin[g][rr][lidx] =
                        (rok && (unsigned)scol < (unsigned)CN_W) ? src[scol] : 0.f;
                }
            }
        }
        __syncthreads();
        // ---- compute: weights via uniform scalar loads ----
        for (int cc = 0; cc < CC; ++cc) {
#pragma unroll
            for (int kh = 0; kh < 3; ++kh) {
#pragma unroll
                for (int kw = 0; kw < 3; ++kw) {
                    float v0 = lin[cc][r2 + 0 + kh][col + kw];
                    float v1 = lin[cc][r2 + 2 + kh][col + kw];
                    float v2 = lin[cc][r2 + 4 + kh][col + kw];
                    float v3 = lin[cc][r2 + 6 + kh][col + kw];
                    const float* wr =
                        wt + (size_t)((ci0 + cc) * 9 + kh * 3 + kw) * CO + co0;
#pragma unroll
                    for (int o = 0; o < 16; ++o) {
                        const float w = wr[o];      // wave-uniform -> s_load
                        acc[0][o] = fmaf(v0, w, acc[0][o]);
                        acc[1][o] = fmaf(v1, w, acc[1][o]);
                        acc[2][o] = fmaf(v2, w, acc[2][o]);
                        acc[3][o] = fmaf(v3, w, acc[3][o]);
                    }
                }
            }
        }
        __syncthreads();
    }
#pragma unroll
    for (int px = 0; px < 4; ++px) {
        const int h = h0 + r2 + 2 * px;
#pragma unroll
        for (int o = 0; o < 16; ++o) {
            float v = acc[px][o] + bias[co0 + o];
            v = v > 0.f ? v : 0.f;
            out[(((size_t)b * CO + co0 + o) * CN_H + h) * CN_W + col] = v;
        }
    }
}

__global__ __launch_bounds__(256) void conv_a_k(   // cls1: 64 -> 128
    const float* __restrict__ in, const float* __restrict__ wt,
    const float* __restrict__ bias, float* __restrict__ out, int CO)
{ conv3x3_body<64>(in, wt, bias, out, CO); }

__global__ __launch_bounds__(256) void conv_b_k(   // cls2: 128 -> 128
    const float* __restrict__ in, const float* __restrict__ wt,
    const float* __restrict__ bias, float* __restrict__ out, int CO)
{ conv3x3_body<128>(in, wt, bias, out, CO); }

// ---------------------------------------------------------------------------
// 1x1 cls: 128 -> 80, f64 accumulate, bias, round to f32. og-fastest decode
// + XCD swizzle (h2 read from HBM once). Proven R7 body.
// ---------------------------------------------------------------------------
__global__ __launch_bounds__(256) void conv1x1_cls_k(
    const float* __restrict__ h2, const float* __restrict__ wgt,
    const float* __restrict__ bias, float* __restrict__ logits)
{
    constexpr int CI = 128;
    const int wg = xcd_swz(blockIdx.x, gridDim.x);
    const int og = wg % 5;
    const int pb = wg / 5;
    const int b  = pb / 64;
    const int p  = (pb % 64) * 256 + threadIdx.x;
    const int o0 = og * 16;

    __shared__ double lw[CI][16];
    for (int e = threadIdx.x; e < CI * 16; e += 256) {
        int ci = e / 16, o = e % 16;
        lw[ci][o] = (double)wgt[(size_t)(o0 + o) * CI + ci];
    }
    __syncthreads();

    double acc[16];
#pragma unroll
    for (int o = 0; o < 16; ++o) acc[o] = 0.0;

    for (int ci = 0; ci < CI; ++ci) {
        double v = (double)h2[((size_t)b * CI + ci) * CN_HW + p];
#pragma unroll
        for (int o = 0; o < 16; ++o) acc[o] += v * lw[ci][o];
    }
#pragma unroll
    for (int o = 0; o < 16; ++o)
        logits[((size_t)b * CN_CLS + o0 + o) * CN_HW + p] =
            (float)(acc[o] + (double)bias[o0 + o]);
}

// ---------------------------------------------------------------------------
// NMS + per-class top-100 (proven R5-R7 bitonic + fallback).
// ---------------------------------------------------------------------------
#define NMS_CAP 2048

__global__ __launch_bounds__(256) void nms_topk_k(
    const float* __restrict__ logits,
    float* __restrict__ pc_logit, int* __restrict__ pc_ind, int b0)
{
    __shared__ float sc[CN_HW];
    __shared__ unsigned long long cand[NMS_CAP];
    __shared__ int   cnt;
    __shared__ float rv[4];
    __shared__ int   ri[4];
    __shared__ int   pick;

    const int bc = blockIdx.x;
    const int bl = bc / CN_CLS;
    const int c  = bc % CN_CLS;
    const int bg = b0 + bl;
    const int t  = threadIdx.x;
    const float* L = logits + (size_t)bc * CN_HW;

    if (t == 0) cnt = 0;
    {
        const float4* L4 = (const float4*)L;
        float4* s4 = (float4*)sc;
        for (int p = t; p < CN_HW / 4; p += 256) s4[p] = L4[p];
    }
    __syncthreads();

    unsigned long long flags = 0;
    for (int k = 0; k < 64; ++k) {
        const int p   = t + 256 * k;
        const int row = p >> 7, cl = p & 127;
        const float c0 = sc[p];
        bool mx = true;
#pragma unroll
        for (int dr = -1; dr <= 1; ++dr)
#pragma unroll
            for (int dc = -1; dc <= 1; ++dc) {
                if (dr == 0 && dc == 0) continue;
                int rr = row + dr, cc2 = cl + dc;
                if ((unsigned)rr < (unsigned)CN_H && (unsigned)cc2 < (unsigned)CN_W)
                    if (sc[(rr << 7) + cc2] > c0) mx = false;
            }
        if (mx) flags |= 1ull << k;
    }
    __syncthreads();

    {
        unsigned long long f = flags;
        while (f) {
            int k = __ffsll((long long)f) - 1;
            f &= f - 1;
            const int p = t + 256 * k;
            const int slot = atomicAdd(&cnt, 1);
            if (slot < NMS_CAP)
                cand[slot] = ((unsigned long long)ordf(sc[p]) << 32) | (unsigned)(~p);
        }
    }
    __syncthreads();
    const int M = cnt;

    if (M >= CN_K && M <= NMS_CAP) {
        int P = 128;
        while (P < M) P <<= 1;
        for (int i = M + t; i < P; i += 256) cand[i] = 0ull;
        __syncthreads();
        for (int k = 2; k <= P; k <<= 1) {
            for (int j = k >> 1; j > 0; j >>= 1) {
                for (int n = t; n < (P >> 1); n += 256) {
                    const int i = ((n & ~(j - 1)) << 1) | (n & (j - 1));
                    const int m = i | j;
                    const unsigned long long a = cand[i], bqq = cand[m];
                    const bool up = ((i & k) == 0);
                    if (up ? (a < bqq) : (a > bqq)) { cand[i] = bqq; cand[m] = a; }
                }
                __syncthreads();
            }
        }
        if (t < CN_K) {
            const unsigned long long key = cand[t];
            const int p = (int)(~(unsigned)key) & 0xFFFF;
            pc_logit[(size_t)bg * 8000 + c * CN_K + t] = unordf((unsigned)(key >> 32));
            pc_ind  [(size_t)bg * 8000 + c * CN_K + t] = p;
        }
    } else {
        unsigned long long removed = 0;
        for (int it = 0; it < CN_K; ++it) {
            float bv = -INFINITY;
            int   bi = 0x7fffffff;
            for (int k = 0; k < 64; ++k) {
                if ((removed >> k) & 1) continue;
                const int p = t + 256 * k;
                const float v = ((flags >> k) & 1) ? sc[p] : NEG_SENT;
                if (v > bv || (v == bv && p < bi)) { bv = v; bi = p; }
            }
#pragma unroll
            for (int off = 32; off; off >>= 1) {
                float ov = __shfl_down(bv, off);
                int   oi = __shfl_down(bi, off);
                if (ov > bv || (ov == bv && oi < bi)) { bv = ov; bi = oi; }
            }
            const int wid = t >> 6;
            if ((t & 63) == 0) { rv[wid] = bv; ri[wid] = bi; }
            __syncthreads();
            if (t == 0) {
                for (int wv = 1; wv < 4; ++wv)
                    if (rv[wv] > bv || (rv[wv] == bv && ri[wv] < bi)) { bv = rv[wv]; bi = ri[wv]; }
                pc_logit[(size_t)bg * 8000 + c * CN_K + it] = bv;
                pc_ind  [(size_t)bg * 8000 + c * CN_K + it] = bi;
                pick = bi;
            }
            __syncthreads();
            const int pk = pick;
            if ((pk & 255) == t) removed |= 1ull << (pk >> 8);
            __syncthreads();
        }
    }
}

// ---------------------------------------------------------------------------
// Global top-100: bitonic sort of 8192 keys; writes (ind, cls, logit-bits).
// ---------------------------------------------------------------------------
__global__ __launch_bounds__(256) void global_topk_k(
    const float* __restrict__ pc_logit, const int* __restrict__ pc_ind,
    int* __restrict__ sel)
{
    constexpr int N = CN_CLS * CN_K;
    constexpr int P = 8192;
    __shared__ unsigned long long gk[P];

    const int b = blockIdx.x;
    const int t = threadIdx.x;

    for (int n = t; n < P; n += 256) {
        unsigned long long key = 0ull;
        if (n < N) {
            const float v = pc_logit[(size_t)b * N + n];
            key = ((unsigned long long)ordf(v) << 32) | (unsigned)(~n);
        }
        gk[n] = key;
    }
    __syncthreads();

    for (int k = 2; k <= P; k <<= 1) {
        for (int j = k >> 1; j > 0; j >>= 1) {
            for (int n = t; n < (P >> 1); n += 256) {
                const int i = ((n & ~(j - 1)) << 1) | (n & (j - 1));
                const int m = i | j;
                const unsigned long long a = gk[i], bqq = gk[m];
                const bool up = ((i & k) == 0);
                if (up ? (a < bqq) : (a > bqq)) { gk[i] = bqq; gk[m] = a; }
            }
            __syncthreads();
        }
    }

    if (t < CN_K) {
        const unsigned long long key = gk[t];
        int flat = (int)(~(unsigned)key) & 0x3FFF;
        if (flat >= N) flat = N - 1;                 // sentinel guard
        const float logit = unordf((unsigned)(key >> 32));
        sel[((size_t)b * CN_K + t) * 3 + 0] = pc_ind[(size_t)b * N + flat];
        sel[((size_t)b * CN_K + t) * 3 + 1] = flat / CN_K;
        sel[((size_t)b * CN_K + t) * 3 + 2] = (int)__float_as_uint(logit);
    }
}

// ---------------------------------------------------------------------------
// Sparse wh + bbox assembly: one block per (b, k). Computes the wh head only
// at the selected pixel: x 5x5 window -> g1 at 9 positions -> g2 -> wh[4].
// f32; tolerance is 10.08 (bf16-rounded compare) so chain order is free.
// ---------------------------------------------------------------------------
__global__ __launch_bounds__(256) void whbbox_k(
    const float* __restrict__ x,
    const float* __restrict__ w1, const float* __restrict__ b1,
    const float* __restrict__ w2, const float* __restrict__ b2,
    const float* __restrict__ w3, const float* __restrict__ b3,
    const int* __restrict__ sel, float* __restrict__ out)
{
    __shared__ float xw[64][25];     // x window, ci-major
    __shared__ float g1s[9][64];
    __shared__ float g2s[64];
    __shared__ float whs[4];

    const int bk = blockIdx.x;
    const int b  = bk / CN_K;
    const int k  = bk % CN_K;
    const int t  = threadIdx.x;

    const int   ind   = sel[((size_t)b * CN_K + k) * 3 + 0];
    const int   cls   = sel[((size_t)b * CN_K + k) * 3 + 1];
    const float logit = __uint_as_float((unsigned)sel[((size_t)b * CN_K + k) * 3 + 2]);
    const int   py = ind >> 7, px = ind & 127;

    // stage x 5x5 window (zeros outside image)
    for (int e = t; e < 64 * 25; e += 256) {
        const int c = e / 25, r = e % 25;
        const int qy = py + r / 5 - 2, qx = px + r % 5 - 2;
        float v = 0.f;
        if ((unsigned)qy < (unsigned)CN_H && (unsigned)qx < (unsigned)CN_W)
            v = x[(((size_t)b * 64 + c) * CN_H + qy) * CN_W + qx];
        xw[c][r] = v;
    }
    __syncthreads();

    // g1 at 9 positions x 64 channels
    for (int e = t; e < 576; e += 256) {
        const int ci = e & 63, qp = e >> 6;        // qp 0..8
        const int qdy = qp / 3 - 1, qdx = qp % 3 - 1;
        const int qy = py + qdy, qx = px + qdx;
        float s = 0.f;
        if ((unsigned)qy < (unsigned)CN_H && (unsigned)qx < (unsigned)CN_W) {
            const float* wp = w1 + (size_t)ci * 64 * 9;
            for (int cj = 0; cj < 64; ++cj) {
#pragma unroll
                for (int jh = 0; jh < 3; ++jh)
#pragma unroll
                    for (int jw = 0; jw < 3; ++jw)
                        s = fmaf(xw[cj][(qdy + jh + 1) * 5 + (qdx + jw + 1)],
                                 wp[cj * 9 + jh * 3 + jw], s);
            }
            s += b1[ci];
            s = s > 0.f ? s : 0.f;
        }
        g1s[qp][ci] = s;
    }
    __syncthreads();

    // g2 at center, 64 channels
    if (t < 64) {
        const int oc = t;
        const float* wp = w2 + (size_t)oc * 64 * 9;
        float s = 0.f;
        for (int ci = 0; ci < 64; ++ci) {
#pragma unroll
            for (int kh = 0; kh < 3; ++kh)
#pragma unroll
                for (int kw = 0; kw < 3; ++kw)
                    s = fmaf(g1s[kh * 3 + kw][ci], wp[ci * 9 + kh * 3 + kw], s);
        }
        s += b2[oc];
        g2s[oc] = s > 0.f ? s : 0.f;
    }
    __syncthreads();

    if (t < 4) {
        float s = 0.f;
        const float* wp = w3 + (size_t)t * 64;
        for (int oc = 0; oc < 64; ++oc) s = fmaf(g2s[oc], wp[oc], s);
        s += b3[t];
        s = s > 0.f ? s : 0.f;
        whs[t] = s * 16.0f;
    }
    __syncthreads();

    if (t == 0) {
        const float score = (float)(1.0 / (1.0 + exp(-(double)logit)));
        const float ys = (float)py * 4.0f;
        const float xs = (float)px * 4.0f;
        float* row = out + ((size_t)b * CN_K + k) * 6;
        row[0] = xs - whs[0];
        row[1] = ys - whs[1];
        row[2] = xs + whs[2];
        row[3] = ys + whs[3];
        row[4] = score;
        row[5] = (float)cls;
        out[CN_B * CN_K * 6 + b * CN_K + k] = (score > 0.01f) ? 1.0f : 0.0f;
    }
}

// ---------------------------------------------------------------------------
extern "C" void kernel_launch(void* const* d_in, const int* in_sizes, int n_in,
                              void* d_out, int out_size, void* d_ws, size_t ws_size,
                              hipStream_t stream)
{
    (void)in_sizes; (void)n_in; (void)out_size;

    const float* x      = (const float*)d_in[0];
    const float* cls_w1 = (const float*)d_in[1];
    const float* cls_b1 = (const float*)d_in[2];
    const float* cls_w2 = (const float*)d_in[3];
    const float* cls_b2 = (const float*)d_in[4];
    const float* cls_w3 = (const float*)d_in[5];
    const float* cls_b3 = (const float*)d_in[6];
    const float* wh_w1  = (const float*)d_in[7];
    const float* wh_b1  = (const float*)d_in[8];
    const float* wh_w2  = (const float*)d_in[9];
    const float* wh_b2  = (const float*)d_in[10];
    const float* wh_w3  = (const float*)d_in[11];
    const float* wh_b3  = (const float*)d_in[12];
    float* out = (float*)d_out;

    // Workspace: persistent first, then per-chunk regions A (h1/logits), B (h2).
    const size_t SZ_PCS = 512000u, SZ_PCI = 512000u;
    const size_t SZ_WT1 = 294912u, SZ_WT2 = 589824u, SZ_SEL = 19200u;
    const size_t PERS = SZ_PCS + SZ_PCI + SZ_WT1 + SZ_WT2 + SZ_SEL; // 1,927,936
    const size_t PER_IMG = 16777216u;   // 8.39 MB (h1/logits) + 8.39 MB (h2)

    int Bc = 1;
    if (ws_size > PERS) {
        size_t m = (ws_size - PERS) / PER_IMG;
        Bc = (int)(m < 1 ? 1 : (m > 16 ? 16 : m));
    }

    char* ws = (char*)d_ws;
    float* pc_s = (float*)ws;
    int*   pc_i = (int*)(ws + SZ_PCS);
    float* wt1  = (float*)(ws + SZ_PCS + SZ_PCI);
    float* wt2  = (float*)(ws + SZ_PCS + SZ_PCI + SZ_WT1);
    int*   sel  = (int*)(ws + SZ_PCS + SZ_PCI + SZ_WT1 + SZ_WT2);
    char*  regA = ws + PERS;
    char*  regB = regA + (size_t)Bc * 8388608u;

    dim3 blk(256);

    // one-time weight transposes (bit-copies)
    wtr_k<<<dim3((64 * 9 * 128 + 255) / 256), blk, 0, stream>>>(cls_w1, wt1, 64, 128);
    wtr_k<<<dim3((128 * 9 * 128 + 255) / 256), blk, 0, stream>>>(cls_w2, wt2, 128, 128);

    for (int b0 = 0; b0 < CN_B; b0 += Bc) {
        const int Bcur = (CN_B - b0 < Bc) ? (CN_B - b0) : Bc;
        const float* xc = x + (size_t)b0 * 64 * CN_HW;
        float* h1     = (float*)regA;
        float* h2     = (float*)regB;
        float* logits = (float*)regA;

        conv_a_k<<<dim3(Bcur * 16 * 8), blk, 0, stream>>>(xc, wt1, cls_b1, h1, 128);
        conv_b_k<<<dim3(Bcur * 16 * 8), blk, 0, stream>>>(h1, wt2, cls_b2, h2, 128);
        conv1x1_cls_k<<<dim3(Bcur * 64 * 5), blk, 0, stream>>>(h2, cls_w3, cls_b3, logits);
        nms_topk_k<<<dim3(Bcur * CN_CLS), blk, 0, stream>>>(logits, pc_s, pc_i, b0);
    }

    global_topk_k<<<dim3(CN_B), blk, 0, stream>>>(pc_s, pc_i, sel);
    whbbox_k<<<dim3(CN_B * CN_K), blk, 0, stream>>>(
        x, wh_w1, wh_b1, wh_w2, wh_b2, wh_w3, wh_b3, sel, out);
}

// Round 9
// 2814.633 us; speedup vs baseline: 1.3232x; 1.0655x over previous
//
#include <hip/hip_runtime.h>
#include <cmath>
#include <cstdint>
#include <cfloat>

// ---------------------------------------------------------------------------
// CenterNet head, MI355X. Round 9: ping-pong double-buffered convs (1 barrier
// per ci-chunk), low-LDS NMS (global-read flags, R4-proven).
// Numerics contract (proven R3-R8, absmax 0.0):
//   - cls 3x3 convs: f32 fmaf chains, EXACT per-output order (ci asc, kh, kw).
//   - cls 1x1: f64 accum (ci 0..127) -> correctly-rounded f32 logits.
//   - Selection on f32 logits, ties by lowest index.
//   - wh: sparse f32 recompute at selected pixels (tolerance 10.08).
// ---------------------------------------------------------------------------

#define CN_B   16
#define CN_H   128
#define CN_W   128
#define CN_HW  16384
#define CN_CLS 80
#define CN_K   100
#define NEG_SENT (-3.402823466e+38f)

__device__ __forceinline__ unsigned ordf(float v) {
    unsigned b = __float_as_uint(v);
    return (b >> 31) ? ~b : (b | 0x80000000u);
}
__device__ __forceinline__ float unordf(unsigned o) {
    return __uint_as_float((o >> 31) ? (o & 0x7fffffffu) : ~o);
}

// Bijective chunked XCD transform (m204): XCD x gets a contiguous chunk.
__device__ __forceinline__ int xcd_swz(int bid, int nwg) {
    const int q = nwg >> 3, r = nwg & 7;
    const int x = bid & 7, off = bid >> 3;
    return (x < r ? x * (q + 1) : r * (q + 1) + (x - r) * q) + off;
}

// ---------------------------------------------------------------------------
// Weight transpose (bit-copy): wt[(ci*9+tap)*CO + co] = w[co][ci][tap].
// ---------------------------------------------------------------------------
__global__ __launch_bounds__(256) void wtr_k(
    const float* __restrict__ w, float* __restrict__ wt, int CI, int CO)
{
    const int e = blockIdx.x * 256 + threadIdx.x;
    const int n = CI * 9 * CO;
    if (e < n) {
        const int co = e % CO;
        const int rest = e / CO;            // ci*9 + tap
        wt[e] = w[(size_t)co * CI * 9 + rest];
    }
}

// ---------------------------------------------------------------------------
// f32 3x3 conv, pad 1, bias + ReLU. Tile: 8 rows x 128 cols x 16 oc. CC=4,
// ping-pong LDS (stage chunk k+1 before computing chunk k; ONE barrier/chunk).
// Weights via wave-uniform scalar loads from transposed layout.
// Per-(px,o) fmaf chain: (ci0 asc, cc, kh, kw) — IDENTICAL bits to R3-R8.
// grid.x = Bc * 16 * (CO/16), co-tile fastest + XCD swizzle.
// ---------------------------------------------------------------------------
template<int CI>
__device__ __forceinline__ void conv3x3_body(
    const float* __restrict__ in, const float* __restrict__ wt,
    const float* __restrict__ bias, float* __restrict__ out, int CO)
{
    constexpr int CC = 4;
    const int wg  = xcd_swz(blockIdx.x, gridDim.x);
    const int cob = CO >> 4;
    const int co0 = (wg % cob) * 16;
    const int tmp = wg / cob;
    const int h0  = (tmp & 15) * 8;
    const int b   = tmp >> 4;

    __shared__ float lin[2][CC][10][132];   // 42.2 KB ping-pong

    const int t   = threadIdx.x;
    const int col = t & 127;
    const int r2  = t >> 7;              // 0..1
    const int g   = t >> 6;              // staging cc 0..3
    const int ln  = t & 63;

    float acc[4][16];
#pragma unroll
    for (int px = 0; px < 4; ++px)
#pragma unroll
        for (int o = 0; o < 16; ++o) acc[px][o] = 0.f;

    // stage chunk ci0 into buffer bf
    auto stage = [&](int ci0, int bf) {
        const float* base = in + (((size_t)b * CI + ci0 + g) * CN_H) * CN_W;
#pragma unroll
        for (int rr = 0; rr < 10; ++rr) {
            const int srow = h0 - 1 + rr;
            const bool rok = (unsigned)srow < (unsigned)CN_H;
            const float* src = base + srow * CN_W;
#pragma unroll
            for (int q = 0; q < 2; ++q) {
                const int lidx = ln + 64 * q;
                const int scol = lidx - 1;
                lin[bf][g][rr][lidx] =
                    (rok && (unsigned)scol < (unsigned)CN_W) ? src[scol] : 0.f;
            }
            if (ln < 2) {
                const int lidx = 128 + ln;
                const int scol = lidx - 1;
                lin[bf][g][rr][lidx] =
                    (rok && (unsigned)scol < (unsigned)CN_W) ? src[scol] : 0.f;
            }
        }
    };

    stage(0, 0);
    __syncthreads();

    int bf = 0;
    for (int ci0 = 0; ci0 < CI; ci0 += CC) {
        if (ci0 + CC < CI) stage(ci0 + CC, bf ^ 1);   // prefetch next chunk
        // ---- compute: weights via uniform scalar loads; EXACT chain ----
        for (int cc = 0; cc < CC; ++cc) {
#pragma unroll
            for (int kh = 0; kh < 3; ++kh) {
#pragma unroll
                for (int kw = 0; kw < 3; ++kw) {
                    float v0 = lin[bf][cc][r2 + 0 + kh][col + kw];
                    float v1 = lin[bf][cc][r2 + 2 + kh][col + kw];
                    float v2 = lin[bf][cc][r2 + 4 + kh][col + kw];
                    float v3 = lin[bf][cc][r2 + 6 + kh][col + kw];
                    const float* wr =
                        wt + (size_t)((ci0 + cc) * 9 + kh * 3 + kw) * CO + co0;
#pragma unroll
                    for (int o = 0; o < 16; ++o) {
                        const float w = wr[o];      // wave-uniform -> s_load
                        acc[0][o] = fmaf(v0, w, acc[0][o]);
                        acc[1][o] = fmaf(v1, w, acc[1][o]);
                        acc[2][o] = fmaf(v2, w, acc[2][o]);
                        acc[3][o] = fmaf(v3, w, acc[3][o]);
                    }
                }
            }
        }
        __syncthreads();
        bf ^= 1;
    }

#pragma unroll
    for (int px = 0; px < 4; ++px) {
        const int h = h0 + r2 + 2 * px;
#pragma unroll
        for (int o = 0; o < 16; ++o) {
            float v = acc[px][o] + bias[co0 + o];
            v = v > 0.f ? v : 0.f;
            out[(((size_t)b * CO + co0 + o) * CN_H + h) * CN_W + col] = v;
        }
    }
}

__global__ __launch_bounds__(256) void conv_a_k(   // cls1: 64 -> 128
    const float* __restrict__ in, const float* __restrict__ wt,
    const float* __restrict__ bias, float* __restrict__ out, int CO)
{ conv3x3_body<64>(in, wt, bias, out, CO); }

__global__ __launch_bounds__(256) void conv_b_k(   // cls2: 128 -> 128
    const float* __restrict__ in, const float* __restrict__ wt,
    const float* __restrict__ bias, float* __restrict__ out, int CO)
{ conv3x3_body<128>(in, wt, bias, out, CO); }

// ---------------------------------------------------------------------------
// 1x1 cls: 128 -> 80, f64 accumulate, bias, round to f32. og-fastest decode
// + XCD swizzle (h2 HBM-read once). Proven R7/R8 body.
// ---------------------------------------------------------------------------
__global__ __launch_bounds__(256) void conv1x1_cls_k(
    const float* __restrict__ h2, const float* __restrict__ wgt,
    const float* __restrict__ bias, float* __restrict__ logits)
{
    constexpr int CI = 128;
    const int wg = xcd_swz(blockIdx.x, gridDim.x);
    const int og = wg % 5;
    const int pb = wg / 5;
    const int b  = pb / 64;
    const int p  = (pb % 64) * 256 + threadIdx.x;
    const int o0 = og * 16;

    __shared__ double lw[CI][16];
    for (int e = threadIdx.x; e < CI * 16; e += 256) {
        int ci = e / 16, o = e % 16;
        lw[ci][o] = (double)wgt[(size_t)(o0 + o) * CI + ci];
    }
    __syncthreads();

    double acc[16];
#pragma unroll
    for (int o = 0; o < 16; ++o) acc[o] = 0.0;

    for (int ci = 0; ci < CI; ++ci) {
        double v = (double)h2[((size_t)b * CI + ci) * CN_HW + p];
#pragma unroll
        for (int o = 0; o < 16; ++o) acc[o] += v * lw[ci][o];
    }
#pragma unroll
    for (int o = 0; o < 16; ++o)
        logits[((size_t)b * CN_CLS + o0 + o) * CN_HW + p] =
            (float)(acc[o] + (double)bias[o0 + o]);
}

// ---------------------------------------------------------------------------
// NMS + per-class top-100. Flags and candidate values read from GLOBAL
// (logits L3-resident; R4-proven). LDS only for the candidate sort (16.5 KB
// -> high occupancy). Bitonic on (ordered_logit<<32 | ~index); iterative
// argmax fallback (R4 semantics) if M<100 or M>2048.
// ---------------------------------------------------------------------------
#define NMS_CAP 2048

__global__ __launch_bounds__(256) void nms_topk_k(
    const float* __restrict__ logits,
    float* __restrict__ pc_logit, int* __restrict__ pc_ind, int b0)
{
    __shared__ unsigned long long cand[NMS_CAP];
    __shared__ int   cnt;
    __shared__ float rv[4];
    __shared__ int   ri[4];
    __shared__ int   pick;

    const int bc = blockIdx.x;
    const int bl = bc / CN_CLS;
    const int c  = bc % CN_CLS;
    const int bg = b0 + bl;
    const int t  = threadIdx.x;
    const float* L = logits + (size_t)bc * CN_HW;

    if (t == 0) cnt = 0;
    __syncthreads();

    unsigned long long flags = 0;
    for (int k = 0; k < 64; ++k) {
        const int p   = t + 256 * k;
        const int row = p >> 7, cl = p & 127;
        const float c0 = L[p];
        bool mx = true;
#pragma unroll
        for (int dr = -1; dr <= 1; ++dr)
#pragma unroll
            for (int dc = -1; dc <= 1; ++dc) {
                if (dr == 0 && dc == 0) continue;
                int rr = row + dr, cc2 = cl + dc;
                if ((unsigned)rr < (unsigned)CN_H && (unsigned)cc2 < (unsigned)CN_W)
                    if (L[(rr << 7) + cc2] > c0) mx = false;
            }
        if (mx) flags |= 1ull << k;
    }

    {
        unsigned long long f = flags;
        while (f) {
            int k = __ffsll((long long)f) - 1;
            f &= f - 1;
            const int p = t + 256 * k;
            const int slot = atomicAdd(&cnt, 1);
            if (slot < NMS_CAP)
                cand[slot] = ((unsigned long long)ordf(L[p]) << 32) | (unsigned)(~p);
        }
    }
    __syncthreads();
    const int M = cnt;

    if (M >= CN_K && M <= NMS_CAP) {
        int P = 128;
        while (P < M) P <<= 1;
        for (int i = M + t; i < P; i += 256) cand[i] = 0ull;
        __syncthreads();
        for (int k = 2; k <= P; k <<= 1) {
            for (int j = k >> 1; j > 0; j >>= 1) {
                for (int n = t; n < (P >> 1); n += 256) {
                    const int i = ((n & ~(j - 1)) << 1) | (n & (j - 1));
                    const int m = i | j;
                    const unsigned long long a = cand[i], bqq = cand[m];
                    const bool up = ((i & k) == 0);
                    if (up ? (a < bqq) : (a > bqq)) { cand[i] = bqq; cand[m] = a; }
                }
                __syncthreads();
            }
        }
        if (t < CN_K) {
            const unsigned long long key = cand[t];
            const int p = (int)(~(unsigned)key) & 0xFFFF;
            pc_logit[(size_t)bg * 8000 + c * CN_K + t] = unordf((unsigned)(key >> 32));
            pc_ind  [(size_t)bg * 8000 + c * CN_K + t] = p;
        }
    } else {
        // fallback: R4-proven iterative argmax from global
        unsigned long long removed = 0;
        for (int it = 0; it < CN_K; ++it) {
            float bv = -INFINITY;
            int   bi = 0x7fffffff;
            for (int k = 0; k < 64; ++k) {
                if ((removed >> k) & 1) continue;
                const int p = t + 256 * k;
                const float v = ((flags >> k) & 1) ? L[p] : NEG_SENT;
                if (v > bv || (v == bv && p < bi)) { bv = v; bi = p; }
            }
#pragma unroll
            for (int off = 32; off; off >>= 1) {
                float ov = __shfl_down(bv, off);
                int   oi = __shfl_down(bi, off);
                if (ov > bv || (ov == bv && oi < bi)) { bv = ov; bi = oi; }
            }
            const int wid = t >> 6;
            if ((t & 63) == 0) { rv[wid] = bv; ri[wid] = bi; }
            __syncthreads();
            if (t == 0) {
                for (int wv = 1; wv < 4; ++wv)
                    if (rv[wv] > bv || (rv[wv] == bv && ri[wv] < bi)) { bv = rv[wv]; bi = ri[wv]; }
                pc_logit[(size_t)bg * 8000 + c * CN_K + it] = bv;
                pc_ind  [(size_t)bg * 8000 + c * CN_K + it] = bi;
                pick = bi;
            }
            __syncthreads();
            const int pk = pick;
            if ((pk & 255) == t) removed |= 1ull << (pk >> 8);
            __syncthreads();
        }
    }
}

// ---------------------------------------------------------------------------
// Global top-100: bitonic sort of 8192 keys; writes (ind, cls, logit-bits).
// ---------------------------------------------------------------------------
__global__ __launch_bounds__(256) void global_topk_k(
    const float* __restrict__ pc_logit, const int* __restrict__ pc_ind,
    int* __restrict__ sel)
{
    constexpr int N = CN_CLS * CN_K;
    constexpr int P = 8192;
    __shared__ unsigned long long gk[P];

    const int b = blockIdx.x;
    const int t = threadIdx.x;

    for (int n = t; n < P; n += 256) {
        unsigned long long key = 0ull;
        if (n < N) {
            const float v = pc_logit[(size_t)b * N + n];
            key = ((unsigned long long)ordf(v) << 32) | (unsigned)(~n);
        }
        gk[n] = key;
    }
    __syncthreads();

    for (int k = 2; k <= P; k <<= 1) {
        for (int j = k >> 1; j > 0; j >>= 1) {
            for (int n = t; n < (P >> 1); n += 256) {
                const int i = ((n & ~(j - 1)) << 1) | (n & (j - 1));
                const int m = i | j;
                const unsigned long long a = gk[i], bqq = gk[m];
                const bool up = ((i & k) == 0);
                if (up ? (a < bqq) : (a > bqq)) { gk[i] = bqq; gk[m] = a; }
            }
            __syncthreads();
        }
    }

    if (t < CN_K) {
        const unsigned long long key = gk[t];
        int flat = (int)(~(unsigned)key) & 0x3FFF;
        if (flat >= N) flat = N - 1;                 // sentinel guard
        const float logit = unordf((unsigned)(key >> 32));
        sel[((size_t)b * CN_K + t) * 3 + 0] = pc_ind[(size_t)b * N + flat];
        sel[((size_t)b * CN_K + t) * 3 + 1] = flat / CN_K;
        sel[((size_t)b * CN_K + t) * 3 + 2] = (int)__float_as_uint(logit);
    }
}

// ---------------------------------------------------------------------------
// Sparse wh + bbox assembly: one block per (b, k). wh head computed only at
// the selected pixel (x 5x5 window -> g1 at 9 pos -> g2 -> wh[4]). f32.
// ---------------------------------------------------------------------------
__global__ __launch_bounds__(256) void whbbox_k(
    const float* __restrict__ x,
    const float* __restrict__ w1, const float* __restrict__ b1,
    const float* __restrict__ w2, const float* __restrict__ b2,
    const float* __restrict__ w3, const float* __restrict__ b3,
    const int* __restrict__ sel, float* __restrict__ out)
{
    __shared__ float xw[64][25];
    __shared__ float g1s[9][64];
    __shared__ float g2s[64];
    __shared__ float whs[4];

    const int bk = blockIdx.x;
    const int b  = bk / CN_K;
    const int k  = bk % CN_K;
    const int t  = threadIdx.x;

    const int   ind   = sel[((size_t)b * CN_K + k) * 3 + 0];
    const int   cls   = sel[((size_t)b * CN_K + k) * 3 + 1];
    const float logit = __uint_as_float((unsigned)sel[((size_t)b * CN_K + k) * 3 + 2]);
    const int   py = ind >> 7, px = ind & 127;

    for (int e = t; e < 64 * 25; e += 256) {
        const int c = e / 25, r = e % 25;
        const int qy = py + r / 5 - 2, qx = px + r % 5 - 2;
        float v = 0.f;
        if ((unsigned)qy < (unsigned)CN_H && (unsigned)qx < (unsigned)CN_W)
            v = x[(((size_t)b * 64 + c) * CN_H + qy) * CN_W + qx];
        xw[c][r] = v;
    }
    __syncthreads();

    for (int e = t; e < 576; e += 256) {
        const int ci = e & 63, qp = e >> 6;
        const int qdy = qp / 3 - 1, qdx = qp % 3 - 1;
        const int qy = py + qdy, qx = px + qdx;
        float s = 0.f;
        if ((unsigned)qy < (unsigned)CN_H && (unsigned)qx < (unsigned)CN_W) {
            const float* wp = w1 + (size_t)ci * 64 * 9;
            for (int cj = 0; cj < 64; ++cj) {
#pragma unroll
                for (int jh = 0; jh < 3; ++jh)
#pragma unroll
                    for (int jw = 0; jw < 3; ++jw)
                        s = fmaf(xw[cj][(qdy + jh + 1) * 5 + (qdx + jw + 1)],
                                 wp[cj * 9 + jh * 3 + jw], s);
            }
            s += b1[ci];
            s = s > 0.f ? s : 0.f;
        }
        g1s[qp][ci] = s;
    }
    __syncthreads();

    if (t < 64) {
        const int oc = t;
        const float* wp = w2 + (size_t)oc * 64 * 9;
        float s = 0.f;
        for (int ci = 0; ci < 64; ++ci) {
#pragma unroll
            for (int kh = 0; kh < 3; ++kh)
#pragma unroll
                for (int kw = 0; kw < 3; ++kw)
                    s = fmaf(g1s[kh * 3 + kw][ci], wp[ci * 9 + kh * 3 + kw], s);
        }
        s += b2[oc];
        g2s[oc] = s > 0.f ? s : 0.f;
    }
    __syncthreads();

    if (t < 4) {
        float s = 0.f;
        const float* wp = w3 + (size_t)t * 64;
        for (int oc = 0; oc < 64; ++oc) s = fmaf(g2s[oc], wp[oc], s);
        s += b3[t];
        s = s > 0.f ? s : 0.f;
        whs[t] = s * 16.0f;
    }
    __syncthreads();

    if (t == 0) {
        const float score = (float)(1.0 / (1.0 + exp(-(double)logit)));
        const float ys = (float)py * 4.0f;
        const float xs = (float)px * 4.0f;
        float* row = out + ((size_t)b * CN_K + k) * 6;
        row[0] = xs - whs[0];
        row[1] = ys - whs[1];
        row[2] = xs + whs[2];
        row[3] = ys + whs[3];
        row[4] = score;
        row[5] = (float)cls;
        out[CN_B * CN_K * 6 + b * CN_K + k] = (score > 0.01f) ? 1.0f : 0.0f;
    }
}

// ---------------------------------------------------------------------------
extern "C" void kernel_launch(void* const* d_in, const int* in_sizes, int n_in,
                              void* d_out, int out_size, void* d_ws, size_t ws_size,
                              hipStream_t stream)
{
    (void)in_sizes; (void)n_in; (void)out_size;

    const float* x      = (const float*)d_in[0];
    const float* cls_w1 = (const float*)d_in[1];
    const float* cls_b1 = (const float*)d_in[2];
    const float* cls_w2 = (const float*)d_in[3];
    const float* cls_b2 = (const float*)d_in[4];
    const float* cls_w3 = (const float*)d_in[5];
    const float* cls_b3 = (const float*)d_in[6];
    const float* wh_w1  = (const float*)d_in[7];
    const float* wh_b1  = (const float*)d_in[8];
    const float* wh_w2  = (const float*)d_in[9];
    const float* wh_b2  = (const float*)d_in[10];
    const float* wh_w3  = (const float*)d_in[11];
    const float* wh_b3  = (const float*)d_in[12];
    float* out = (float*)d_out;

    const size_t SZ_PCS = 512000u, SZ_PCI = 512000u;
    const size_t SZ_WT1 = 294912u, SZ_WT2 = 589824u, SZ_SEL = 19200u;
    const size_t PERS = SZ_PCS + SZ_PCI + SZ_WT1 + SZ_WT2 + SZ_SEL;
    const size_t PER_IMG = 16777216u;   // 8.39 MB (h1/logits) + 8.39 MB (h2)

    int Bc = 1;
    if (ws_size > PERS) {
        size_t m = (ws_size - PERS) / PER_IMG;
        Bc = (int)(m < 1 ? 1 : (m > 16 ? 16 : m));
    }

    char* ws = (char*)d_ws;
    float* pc_s = (float*)ws;
    int*   pc_i = (int*)(ws + SZ_PCS);
    float* wt1  = (float*)(ws + SZ_PCS + SZ_PCI);
    float* wt2  = (float*)(ws + SZ_PCS + SZ_PCI + SZ_WT1);
    int*   sel  = (int*)(ws + SZ_PCS + SZ_PCI + SZ_WT1 + SZ_WT2);
    char*  regA = ws + PERS;
    char*  regB = regA + (size_t)Bc * 8388608u;

    dim3 blk(256);

    wtr_k<<<dim3((64 * 9 * 128 + 255) / 256), blk, 0, stream>>>(cls_w1, wt1, 64, 128);
    wtr_k<<<dim3((128 * 9 * 128 + 255) / 256), blk, 0, stream>>>(cls_w2, wt2, 128, 128);

    for (int b0 = 0; b0 < CN_B; b0 += Bc) {
        const int Bcur = (CN_B - b0 < Bc) ? (CN_B - b0) : Bc;
        const float* xc = x + (size_t)b0 * 64 * CN_HW;
        float* h1     = (float*)regA;
        float* h2     = (float*)regB;
        float* logits = (float*)regA;

        conv_a_k<<<dim3(Bcur * 16 * 8), blk, 0, stream>>>(xc, wt1, cls_b1, h1, 128);
        conv_b_k<<<dim3(Bcur * 16 * 8), blk, 0, stream>>>(h1, wt2, cls_b2, h2, 128);
        conv1x1_cls_k<<<dim3(Bcur * 64 * 5), blk, 0, stream>>>(h2, cls_w3, cls_b3, logits);
        nms_topk_k<<<dim3(Bcur * CN_CLS), blk, 0, stream>>>(logits, pc_s, pc_i, b0);
    }

    global_topk_k<<<dim3(CN_B), blk, 0, stream>>>(pc_s, pc_i, sel);
    whbbox_k<<<dim3(CN_B * CN_K), blk, 0, stream>>>(
        x, wh_w1, wh_b1, wh_w2, wh_b2, wh_w3, wh_b3, sel, out);
}

// Round 10
// 2496.840 us; speedup vs baseline: 1.4916x; 1.1273x over previous
//
#include <hip/hip_runtime.h>
#include <cmath>
#include <cstdint>
#include <cfloat>

// ---------------------------------------------------------------------------
// CenterNet head, MI355X. Round 10: R8 conv bodies (proven fastest), SGPR-path
// f64 1x1 (no LDS weights), 80-way merge-pop global top-k.
// Numerics contract (proven R3-R9, absmax 0.0):
//   - cls 3x3 convs: f32 fmaf chains, EXACT per-output order (ci asc, kh, kw).
//   - cls 1x1: f64 accum (ci 0..127) -> correctly-rounded f32 logits.
//   - Selection on f32 logits, ties by lowest index (u64 key = ordf<<32 | ~i).
//   - wh: sparse f32 recompute at selected pixels (tolerance 10.08).
// ---------------------------------------------------------------------------

#define CN_B   16
#define CN_H   128
#define CN_W   128
#define CN_HW  16384
#define CN_CLS 80
#define CN_K   100
#define NEG_SENT (-3.402823466e+38f)

__device__ __forceinline__ unsigned ordf(float v) {
    unsigned b = __float_as_uint(v);
    return (b >> 31) ? ~b : (b | 0x80000000u);
}
__device__ __forceinline__ float unordf(unsigned o) {
    return __uint_as_float((o >> 31) ? (o & 0x7fffffffu) : ~o);
}

// Bijective chunked XCD transform (m204): XCD x gets a contiguous chunk.
__device__ __forceinline__ int xcd_swz(int bid, int nwg) {
    const int q = nwg >> 3, r = nwg & 7;
    const int x = bid & 7, off = bid >> 3;
    return (x < r ? x * (q + 1) : r * (q + 1) + (x - r) * q) + off;
}

// ---------------------------------------------------------------------------
// 3x3 weight transpose (bit-copy): wt[(ci*9+tap)*CO + co] = w[co][ci][tap].
// ---------------------------------------------------------------------------
__global__ __launch_bounds__(256) void wtr_k(
    const float* __restrict__ w, float* __restrict__ wt, int CI, int CO)
{
    const int e = blockIdx.x * 256 + threadIdx.x;
    const int n = CI * 9 * CO;
    if (e < n) {
        const int co = e % CO;
        const int rest = e / CO;            // ci*9 + tap
        wt[e] = w[(size_t)co * CI * 9 + rest];
    }
}

// 1x1 weight transpose to f64 (exact): wt[ci*80 + o] = (double)w[o*128 + ci].
__global__ __launch_bounds__(256) void wtr1x1_k(
    const float* __restrict__ w, double* __restrict__ wt)
{
    const int e = blockIdx.x * 256 + threadIdx.x;
    if (e < 128 * CN_CLS) {
        const int ci = e / CN_CLS, o = e % CN_CLS;
        wt[e] = (double)w[(size_t)o * 128 + ci];
    }
}

// ---------------------------------------------------------------------------
// f32 3x3 conv, pad 1, bias + ReLU. EXACT R8 body (883 us for conv_b):
// tile 8 rows x 128 cols x 16 oc, CC=4 single-buffer, SGPR weights.
// Per-(px,o) fmaf chain: (ci0 asc, cc, kh, kw) — IDENTICAL bits to R3-R9.
// grid.x = Bc * 16 * (CO/16), co-tile fastest + XCD swizzle.
// ---------------------------------------------------------------------------
template<int CI>
__device__ __forceinline__ void conv3x3_body(
    const float* __restrict__ in, const float* __restrict__ wt,
    const float* __restrict__ bias, float* __restrict__ out, int CO)
{
    constexpr int CC = 4;
    const int wg  = xcd_swz(blockIdx.x, gridDim.x);
    const int cob = CO >> 4;
    const int co0 = (wg % cob) * 16;
    const int tmp = wg / cob;
    const int h0  = (tmp & 15) * 8;
    const int b   = tmp >> 4;

    __shared__ float lin[CC][10][132];   // 21.1 KB

    const int t   = threadIdx.x;
    const int col = t & 127;
    const int r2  = t >> 7;              // 0..1
    const int g   = t >> 6;              // staging cc 0..3
    const int ln  = t & 63;

    float acc[4][16];
#pragma unroll
    for (int px = 0; px < 4; ++px)
#pragma unroll
        for (int o = 0; o < 16; ++o) acc[px][o] = 0.f;

    for (int ci0 = 0; ci0 < CI; ci0 += CC) {
        // ---- input staging (proven R5/R8 form) ----
        {
            const float* base = in + (((size_t)b * CI + ci0 + g) * CN_H) * CN_W;
#pragma unroll
            for (int rr = 0; rr < 10; ++rr) {
                const int srow = h0 - 1 + rr;
                const bool rok = (unsigned)srow < (unsigned)CN_H;
                const float* src = base + srow * CN_W;
#pragma unroll
                for (int q = 0; q < 2; ++q) {
                    const int lidx = ln + 64 * q;
                    const int scol = lidx - 1;
                    lin[g][rr][lidx] =
                        (rok && (unsigned)scol < (unsigned)CN_W) ? src[scol] : 0.f;
                }
                if (ln < 2) {
                    const int lidx = 128 + ln;
                    const int scol = lidx - 1;
                    lin[g][rr][lidx] =
                        (rok && (unsigned)scol < (unsigned)CN_W) ? src[scol] : 0.f;
                }
            }
        }
        __syncthreads();
        // ---- compute: weights via uniform scalar loads; EXACT chain ----
        for (int cc = 0; cc < CC; ++cc) {
#pragma unroll
            for (int kh = 0; kh < 3; ++kh) {
#pragma unroll
                for (int kw = 0; kw < 3; ++kw) {
                    float v0 = lin[cc][r2 + 0 + kh][col + kw];
                    float v1 = lin[cc][r2 + 2 + kh][col + kw];
                    float v2 = lin[cc][r2 + 4 + kh][col + kw];
                    float v3 = lin[cc][r2 + 6 + kh][col + kw];
                    const float* wr =
                        wt + (size_t)((ci0 + cc) * 9 + kh * 3 + kw) * CO + co0;
#pragma unroll
                    for (int o = 0; o < 16; ++o) {
                        const float w = wr[o];      // wave-uniform -> s_load
                        acc[0][o] = fmaf(v0, w, acc[0][o]);
                        acc[1][o] = fmaf(v1, w, acc[1][o]);
                        acc[2][o] = fmaf(v2, w, acc[2][o]);
                        acc[3][o] = fmaf(v3, w, acc[3][o]);
                    }
                }
            }
        }
        __syncthreads();
    }

#pragma unroll
    for (int px = 0; px < 4; ++px) {
        const int h = h0 + r2 + 2 * px;
#pragma unroll
        for (int o = 0; o < 16; ++o) {
            float v = acc[px][o] + bias[co0 + o];
            v = v > 0.f ? v : 0.f;
            out[(((size_t)b * CO + co0 + o) * CN_H + h) * CN_W + col] = v;
        }
    }
}

__global__ __launch_bounds__(256) void conv_a_k(   // cls1: 64 -> 128
    const float* __restrict__ in, const float* __restrict__ wt,
    const float* __restrict__ bias, float* __restrict__ out, int CO)
{ conv3x3_body<64>(in, wt, bias, out, CO); }

__global__ __launch_bounds__(256) void conv_b_k(   // cls2: 128 -> 128
    const float* __restrict__ in, const float* __restrict__ wt,
    const float* __restrict__ bias, float* __restrict__ out, int CO)
{ conv3x3_body<128>(in, wt, bias, out, CO); }

// ---------------------------------------------------------------------------
// 1x1 cls: 128 -> 80, f64 accumulate, SGPR weight path (transposed f64 table,
// wave-uniform reads -> s_load_dwordx + v_fma_f64, no LDS in the loop).
// Per-o chain ci 0..127 ascending; f64 accum -> correctly-rounded f32 logits
// (identical f32 results as R3-R9). og-fastest decode + XCD swizzle.
// ---------------------------------------------------------------------------
__global__ __launch_bounds__(256) void conv1x1_cls_k(
    const float* __restrict__ h2, const double* __restrict__ wt,
    const float* __restrict__ bias, float* __restrict__ logits)
{
    constexpr int CI = 128;
    const int wg = xcd_swz(blockIdx.x, gridDim.x);
    const int og = wg % 5;
    const int pb = wg / 5;
    const int b  = pb / 64;
    const int p  = (pb % 64) * 256 + threadIdx.x;
    const int o0 = og * 16;

    double acc[16];
#pragma unroll
    for (int o = 0; o < 16; ++o) acc[o] = 0.0;

    for (int ci = 0; ci < CI; ++ci) {
        const double v = (double)h2[((size_t)b * CI + ci) * CN_HW + p];
        const double* wr = wt + (size_t)ci * CN_CLS + o0;   // wave-uniform
#pragma unroll
        for (int o = 0; o < 16; ++o) acc[o] = fma(v, wr[o], acc[o]);
    }
#pragma unroll
    for (int o = 0; o < 16; ++o)
        logits[((size_t)b * CN_CLS + o0 + o) * CN_HW + p] =
            (float)(acc[o] + (double)bias[o0 + o]);
}

// ---------------------------------------------------------------------------
// NMS + per-class top-100 (exact R9 body: global-read flags, low LDS).
// ---------------------------------------------------------------------------
#define NMS_CAP 2048

__global__ __launch_bounds__(256) void nms_topk_k(
    const float* __restrict__ logits,
    float* __restrict__ pc_logit, int* __restrict__ pc_ind, int b0)
{
    __shared__ unsigned long long cand[NMS_CAP];
    __shared__ int   cnt;
    __shared__ float rv[4];
    __shared__ int   ri[4];
    __shared__ int   pick;

    const int bc = blockIdx.x;
    const int bl = bc / CN_CLS;
    const int c  = bc % CN_CLS;
    const int bg = b0 + bl;
    const int t  = threadIdx.x;
    const float* L = logits + (size_t)bc * CN_HW;

    if (t == 0) cnt = 0;
    __syncthreads();

    unsigned long long flags = 0;
    for (int k = 0; k < 64; ++k) {
        const int p   = t + 256 * k;
        const int row = p >> 7, cl = p & 127;
        const float c0 = L[p];
        bool mx = true;
#pragma unroll
        for (int dr = -1; dr <= 1; ++dr)
#pragma unroll
            for (int dc = -1; dc <= 1; ++dc) {
                if (dr == 0 && dc == 0) continue;
                int rr = row + dr, cc2 = cl + dc;
                if ((unsigned)rr < (unsigned)CN_H && (unsigned)cc2 < (unsigned)CN_W)
                    if (L[(rr << 7) + cc2] > c0) mx = false;
            }
        if (mx) flags |= 1ull << k;
    }

    {
        unsigned long long f = flags;
        while (f) {
            int k = __ffsll((long long)f) - 1;
            f &= f - 1;
            const int p = t + 256 * k;
            const int slot = atomicAdd(&cnt, 1);
            if (slot < NMS_CAP)
                cand[slot] = ((unsigned long long)ordf(L[p]) << 32) | (unsigned)(~p);
        }
    }
    __syncthreads();
    const int M = cnt;

    if (M >= CN_K && M <= NMS_CAP) {
        int P = 128;
        while (P < M) P <<= 1;
        for (int i = M + t; i < P; i += 256) cand[i] = 0ull;
        __syncthreads();
        for (int k = 2; k <= P; k <<= 1) {
            for (int j = k >> 1; j > 0; j >>= 1) {
                for (int n = t; n < (P >> 1); n += 256) {
                    const int i = ((n & ~(j - 1)) << 1) | (n & (j - 1));
                    const int m = i | j;
                    const unsigned long long a = cand[i], bqq = cand[m];
                    const bool up = ((i & k) == 0);
                    if (up ? (a < bqq) : (a > bqq)) { cand[i] = bqq; cand[m] = a; }
                }
                __syncthreads();
            }
        }
        if (t < CN_K) {
            const unsigned long long key = cand[t];
            const int p = (int)(~(unsigned)key) & 0xFFFF;
            pc_logit[(size_t)bg * 8000 + c * CN_K + t] = unordf((unsigned)(key >> 32));
            pc_ind  [(size_t)bg * 8000 + c * CN_K + t] = p;
        }
    } else {
        unsigned long long removed = 0;
        for (int it = 0; it < CN_K; ++it) {
            float bv = -INFINITY;
            int   bi = 0x7fffffff;
            for (int k = 0; k < 64; ++k) {
                if ((removed >> k) & 1) continue;
                const int p = t + 256 * k;
                const float v = ((flags >> k) & 1) ? L[p] : NEG_SENT;
                if (v > bv || (v == bv && p < bi)) { bv = v; bi = p; }
            }
#pragma unroll
            for (int off = 32; off; off >>= 1) {
                float ov = __shfl_down(bv, off);
                int   oi = __shfl_down(bi, off);
                if (ov > bv || (ov == bv && oi < bi)) { bv = ov; bi = oi; }
            }
            const int wid = t >> 6;
            if ((t & 63) == 0) { rv[wid] = bv; ri[wid] = bi; }
            __syncthreads();
            if (t == 0) {
                for (int wv = 1; wv < 4; ++wv)
                    if (rv[wv] > bv || (rv[wv] == bv && ri[wv] < bi)) { bv = rv[wv]; bi = ri[wv]; }
                pc_logit[(size_t)bg * 8000 + c * CN_K + it] = bv;
                pc_ind  [(size_t)bg * 8000 + c * CN_K + it] = bi;
                pick = bi;
            }
            __syncthreads();
            const int pk = pick;
            if ((pk & 255) == t) removed |= 1ull << (pk >> 8);
            __syncthreads();
        }
    }
}

// ---------------------------------------------------------------------------
// Global top-100 via 80-way merge-pop (per-class lists already sorted desc).
// Keys u64 = (ordf(logit)<<32 | ~flat): pop order == (value desc, flat asc)
// == bitonic/lax.top_k semantics exactly. One block per b; keys in LDS.
// ---------------------------------------------------------------------------
__global__ __launch_bounds__(256) void global_topk_k(
    const float* __restrict__ pc_logit, const int* __restrict__ pc_ind,
    int* __restrict__ sel)
{
    constexpr int N = CN_CLS * CN_K;           // 8000
    __shared__ unsigned long long keys[N];     // 64 KB
    __shared__ unsigned long long heads[128];  // 80 used, rest sentinel
    __shared__ int rcs[CN_CLS];

    const int b = blockIdx.x;
    const int t = threadIdx.x;

    for (int n = t; n < N; n += 256) {
        const float v = pc_logit[(size_t)b * N + n];
        keys[n] = ((unsigned long long)ordf(v) << 32) | (unsigned)(~n);
    }
    if (t >= CN_CLS && t < 128) heads[t] = 0ull;
    __syncthreads();
    if (t < CN_CLS) { heads[t] = keys[t * CN_K]; rcs[t] = 1; }
    __syncthreads();

    for (int it = 0; it < CN_K; ++it) {
        if (t < 64) {
            unsigned long long k0 = heads[t];
            unsigned long long k1 = heads[t + 64];
            unsigned long long bk = (k0 >= k1) ? k0 : k1;
#pragma unroll
            for (int off = 32; off; off >>= 1) {
                unsigned long long ok = __shfl_down(bk, off);
                if (ok > bk) bk = ok;
            }
            if (t == 0) {
                const int flat = (int)(~(unsigned)bk);
                const int c    = flat / CN_K;
                sel[((size_t)b * CN_K + it) * 3 + 0] = pc_ind[(size_t)b * N + flat];
                sel[((size_t)b * CN_K + it) * 3 + 1] = c;
                sel[((size_t)b * CN_K + it) * 3 + 2] = (int)(unsigned)(bk >> 32);
                const int rc = rcs[c]++;
                heads[c] = (rc < CN_K) ? keys[c * CN_K + rc] : 0ull;
            }
        }
        __syncthreads();
    }
}

// ---------------------------------------------------------------------------
// Sparse wh + bbox assembly (proven R8/R9): one block per (b, k).
// ---------------------------------------------------------------------------
__global__ __launch_bounds__(256) void whbbox_k(
    const float* __restrict__ x,
    const float* __restrict__ w1, const float* __restrict__ b1,
    const float* __restrict__ w2, const float* __restrict__ b2,
    const float* __restrict__ w3, const float* __restrict__ b3,
    const int* __restrict__ sel, float* __restrict__ out)
{
    __shared__ float xw[64][25];
    __shared__ float g1s[9][64];
    __shared__ float g2s[64];
    __shared__ float whs[4];

    const int bk = blockIdx.x;
    const int b  = bk / CN_K;
    const int k  = bk % CN_K;
    const int t  = threadIdx.x;

    const int   ind   = sel[((size_t)b * CN_K + k) * 3 + 0];
    const int   cls   = sel[((size_t)b * CN_K + k) * 3 + 1];
    const float logit = __uint_as_float((unsigned)sel[((size_t)b * CN_K + k) * 3 + 2]);
    // logit stored as ordf bits -> decode
    const float lg = unordf((unsigned)__float_as_uint(logit));
    const int   py = ind >> 7, px = ind & 127;

    for (int e = t; e < 64 * 25; e += 256) {
        const int c = e / 25, r = e % 25;
        const int qy = py + r / 5 - 2, qx = px + r % 5 - 2;
        float v = 0.f;
        if ((unsigned)qy < (unsigned)CN_H && (unsigned)qx < (unsigned)CN_W)
            v = x[(((size_t)b * 64 + c) * CN_H + qy) * CN_W + qx];
        xw[c][r] = v;
    }
    __syncthreads();

    for (int e = t; e < 576; e += 256) {
        const int ci = e & 63, qp = e >> 6;
        const int qdy = qp / 3 - 1, qdx = qp % 3 - 1;
        const int qy = py + qdy, qx = px + qdx;
        float s = 0.f;
        if ((unsigned)qy < (unsigned)CN_H && (unsigned)qx < (unsigned)CN_W) {
            const float* wp = w1 + (size_t)ci * 64 * 9;
            for (int cj = 0; cj < 64; ++cj) {
#pragma unroll
                for (int jh = 0; jh < 3; ++jh)
#pragma unroll
                    for (int jw = 0; jw < 3; ++jw)
                        s = fmaf(xw[cj][(qdy + jh + 1) * 5 + (qdx + jw + 1)],
                                 wp[cj * 9 + jh * 3 + jw], s);
            }
            s += b1[ci];
            s = s > 0.f ? s : 0.f;
        }
        g1s[qp][ci] = s;
    }
    __syncthreads();

    if (t < 64) {
        const int oc = t;
        const float* wp = w2 + (size_t)oc * 64 * 9;
        float s = 0.f;
        for (int ci = 0; ci < 64; ++ci) {
#pragma unroll
            for (int kh = 0; kh < 3; ++kh)
#pragma unroll
                for (int kw = 0; kw < 3; ++kw)
                    s = fmaf(g1s[kh * 3 + kw][ci], wp[ci * 9 + kh * 3 + kw], s);
        }
        s += b2[oc];
        g2s[oc] = s > 0.f ? s : 0.f;
    }
    __syncthreads();

    if (t < 4) {
        float s = 0.f;
        const float* wp = w3 + (size_t)t * 64;
        for (int oc = 0; oc < 64; ++oc) s = fmaf(g2s[oc], wp[oc], s);
        s += b3[t];
        s = s > 0.f ? s : 0.f;
        whs[t] = s * 16.0f;
    }
    __syncthreads();

    if (t == 0) {
        const float score = (float)(1.0 / (1.0 + exp(-(double)lg)));
        const float ys = (float)py * 4.0f;
        const float xs = (float)px * 4.0f;
        float* row = out + ((size_t)b * CN_K + k) * 6;
        row[0] = xs - whs[0];
        row[1] = ys - whs[1];
        row[2] = xs + whs[2];
        row[3] = ys + whs[3];
        row[4] = score;
        row[5] = (float)cls;
        out[CN_B * CN_K * 6 + b * CN_K + k] = (score > 0.01f) ? 1.0f : 0.0f;
    }
}

// ---------------------------------------------------------------------------
extern "C" void kernel_launch(void* const* d_in, const int* in_sizes, int n_in,
                              void* d_out, int out_size, void* d_ws, size_t ws_size,
                              hipStream_t stream)
{
    (void)in_sizes; (void)n_in; (void)out_size;

    const float* x      = (const float*)d_in[0];
    const float* cls_w1 = (const float*)d_in[1];
    const float* cls_b1 = (const float*)d_in[2];
    const float* cls_w2 = (const float*)d_in[3];
    const float* cls_b2 = (const float*)d_in[4];
    const float* cls_w3 = (const float*)d_in[5];
    const float* cls_b3 = (const float*)d_in[6];
    const float* wh_w1  = (const float*)d_in[7];
    const float* wh_b1  = (const float*)d_in[8];
    const float* wh_w2  = (const float*)d_in[9];
    const float* wh_b2  = (const float*)d_in[10];
    const float* wh_w3  = (const float*)d_in[11];
    const float* wh_b3  = (const float*)d_in[12];
    float* out = (float*)d_out;

    const size_t SZ_PCS = 512000u, SZ_PCI = 512000u;
    const size_t SZ_WT1 = 294912u, SZ_WT2 = 589824u;
    const size_t SZ_WTC = 81920u;               // 128*80 f64
    const size_t SZ_SEL = 19200u;
    const size_t PERS = SZ_PCS + SZ_PCI + SZ_WT1 + SZ_WT2 + SZ_WTC + SZ_SEL;
    const size_t PER_IMG = 16777216u;

    int Bc = 1;
    if (ws_size > PERS) {
        size_t m = (ws_size - PERS) / PER_IMG;
        Bc = (int)(m < 1 ? 1 : (m > 16 ? 16 : m));
    }

    char* ws = (char*)d_ws;
    float*  pc_s = (float*)ws;
    int*    pc_i = (int*)(ws + SZ_PCS);
    float*  wt1  = (float*)(ws + SZ_PCS + SZ_PCI);
    float*  wt2  = (float*)(ws + SZ_PCS + SZ_PCI + SZ_WT1);
    double* wtc  = (double*)(ws + SZ_PCS + SZ_PCI + SZ_WT1 + SZ_WT2);
    int*    sel  = (int*)(ws + SZ_PCS + SZ_PCI + SZ_WT1 + SZ_WT2 + SZ_WTC);
    char*   regA = ws + PERS;
    char*   regB = regA + (size_t)Bc * 8388608u;

    dim3 blk(256);

    wtr_k<<<dim3((64 * 9 * 128 + 255) / 256), blk, 0, stream>>>(cls_w1, wt1, 64, 128);
    wtr_k<<<dim3((128 * 9 * 128 + 255) / 256), blk, 0, stream>>>(cls_w2, wt2, 128, 128);
    wtr1x1_k<<<dim3((128 * CN_CLS + 255) / 256), blk, 0, stream>>>(cls_w3, wtc);

    for (int b0 = 0; b0 < CN_B; b0 += Bc) {
        const int Bcur = (CN_B - b0 < Bc) ? (CN_B - b0) : Bc;
        const float* xc = x + (size_t)b0 * 64 * CN_HW;
        float* h1     = (float*)regA;
        float* h2     = (float*)regB;
        float* logits = (float*)regA;

        conv_a_k<<<dim3(Bcur * 16 * 8), blk, 0, stream>>>(xc, wt1, cls_b1, h1, 128);
        conv_b_k<<<dim3(Bcur * 16 * 8), blk, 0, stream>>>(h1, wt2, cls_b2, h2, 128);
        conv1x1_cls_k<<<dim3(Bcur * 64 * 5), blk, 0, stream>>>(h2, wtc, cls_b3, logits);
        nms_topk_k<<<dim3(Bcur * CN_CLS), blk, 0, stream>>>(logits, pc_s, pc_i, b0);
    }

    global_topk_k<<<dim3(CN_B), blk, 0, stream>>>(pc_s, pc_i, sel);
    whbbox_k<<<dim3(CN_B * CN_K), blk, 0, stream>>>(
        x, wh_w1, wh_b1, wh_w2, wh_b2, wh_w3, wh_b3, sel, out);
}